// Round 5
// baseline (904.932 us; speedup 1.0000x reference)
//
#include <hip/hip_runtime.h>

// ---------------------------------------------------------------------------
// MagNet link prediction forward, f32 throughout (16-bit quantization of the
// propagated streams failed: complex-ReLU mask flips amplify tiny hr errors
// into O(|hi|) output errors — rounds 3/4). Gather (CSR) formulation.
//
//   P[node][256] f32: (g1r | g1i | g2r | g2i)   g1 = x@W1, g2 = x@W2
//   H[node][64]  f32: starts as x@(W0-W2)+b, accumulates T1, T2 terms
//   U[node][256] f32: (u0 | u1 | u2 | u3)  per-stream prop of g2
// gatherA: H += sum_e c*(g1 of src);  U = per-stream prop of g2
// gatherB: H += 2 * per-stream prop of U; complex ReLU
// Gathers: wave = 4 groups x 16 lanes; group g owns edges k0+g, k0+g+4, ...
// lane reads float4 slices of the 1KB row -> 4 edges in flight per wave.
// Reverse edges reuse forward coefficients with ni -> -ni.
// ---------------------------------------------------------------------------

__device__ __forceinline__ float4 ld4(const float* __restrict__ p) {
  return *reinterpret_cast<const float4*>(p);
}
__device__ __forceinline__ void fmad4(float4& a, float s, const float4& b) {
  a.x += s * b.x; a.y += s * b.y; a.z += s * b.z; a.w += s * b.w;
}
__device__ __forceinline__ void red4(float4& a) {  // sum over lane bits 4,5
#pragma unroll
  for (int o = 16; o < 64; o <<= 1) {
    a.x += __shfl_xor(a.x, o);
    a.y += __shfl_xor(a.y, o);
    a.z += __shfl_xor(a.z, o);
    a.w += __shfl_xor(a.w, o);
  }
}
__device__ __forceinline__ float4 add4(float4 a, float4 b) {
  return make_float4(a.x + b.x, a.y + b.y, a.z + b.z, a.w + b.w);
}

// ---- degree (0.5*w per endpoint) + incident-edge count ----------------------
__global__ void k_deg_count(const int* __restrict__ u, const int* __restrict__ v,
                            const float* __restrict__ w, float* __restrict__ deg,
                            int* __restrict__ cnt, int E) {
  int e = blockIdx.x * 256 + threadIdx.x;
  if (e >= E) return;
  float hw = 0.5f * w[e];
  int a = u[e], b = v[e];
  unsafeAtomicAdd(&deg[a], hw);
  unsafeAtomicAdd(&deg[b], hw);
  atomicAdd(&cnt[a], 1);
  atomicAdd(&cnt[b], 1);
}

// ---- exclusive scan of cnt[N] -> rp ----------------------------------------
__global__ __launch_bounds__(256) void k_scan1(const int* __restrict__ cnt,
                                               int* __restrict__ rp,
                                               int* __restrict__ bsum, int N) {
  __shared__ int sh[256];
  int t = threadIdx.x;
  int base = blockIdx.x * 1024 + t * 4;
  int c0 = (base + 0 < N) ? cnt[base + 0] : 0;
  int c1 = (base + 1 < N) ? cnt[base + 1] : 0;
  int c2 = (base + 2 < N) ? cnt[base + 2] : 0;
  int c3 = (base + 3 < N) ? cnt[base + 3] : 0;
  int s = c0 + c1 + c2 + c3;
  sh[t] = s;
  __syncthreads();
  for (int o = 1; o < 256; o <<= 1) {
    int y = (t >= o) ? sh[t - o] : 0;
    __syncthreads();
    if (t >= o) sh[t] += y;
    __syncthreads();
  }
  int excl = sh[t] - s;
  if (base + 0 < N) rp[base + 0] = excl;
  if (base + 1 < N) rp[base + 1] = excl + c0;
  if (base + 2 < N) rp[base + 2] = excl + c0 + c1;
  if (base + 3 < N) rp[base + 3] = excl + c0 + c1 + c2;
  if (t == 255) bsum[blockIdx.x] = sh[255];
}

__global__ void k_scan2(int* __restrict__ bsum, int NB) {
  if (threadIdx.x == 0 && blockIdx.x == 0) {
    int run = 0;
    for (int i = 0; i < NB; ++i) { int x = bsum[i]; bsum[i] = run; run += x; }
  }
}

__global__ void k_scan3(int* __restrict__ rp, int* __restrict__ nxt,
                        const int* __restrict__ bsum, int N, int twoE) {
  int i = blockIdx.x * 256 + threadIdx.x;
  if (i < N) {
    int val = rp[i] + bsum[i >> 10];
    rp[i] = val;
    nxt[i] = val;
  } else if (i == N) {
    rp[N] = twoE;
  }
}

// ---- scatter edge records: rec[pos] = (src_bits, cr, ci, 0) -----------------
__global__ void k_scatter(const int* __restrict__ u, const int* __restrict__ v,
                          const float* __restrict__ w, const float* __restrict__ deg,
                          int* __restrict__ nxt, float4* __restrict__ rec, int E) {
  int e = blockIdx.x * 256 + threadIdx.x;
  if (e >= E) return;
  int a = u[e], b = v[e];
  float we = w[e];
  float da = deg[a], db = deg[b];
  float ia = da > 0.f ? rsqrtf(da) : 0.f;
  float ib = db > 0.f ? rsqrtf(db) : 0.f;
  float norm = ia * (0.5f * we) * ib;
  float th = 1.57079632679489662f * we;  // 2*pi*q*w, q=0.25
  float sn, cs;
  sincosf(th, &sn, &cs);
  float cr = -norm * cs, ci = -norm * sn;
  int p1 = atomicAdd(&nxt[b], 1);  // forward a->b, coeff (cr, ci)
  rec[p1] = make_float4(__int_as_float(a), cr, ci, 0.f);
  int p2 = atomicAdd(&nxt[a], 1);  // reverse b->a, coeff (cr, -ci)
  rec[p2] = make_float4(__int_as_float(b), cr, -ci, 0.f);
}

// ---- fused 6-stream GEMM: P row + biased H base -----------------------------
template <int K>
__global__ __launch_bounds__(256) void k_gemmF(
    const float* __restrict__ Ar, const float* __restrict__ Ai,
    const float* __restrict__ W,  // [3][K][64]
    const float* __restrict__ bias,
    float* __restrict__ P, float* __restrict__ Hr, float* __restrict__ Hi,
    int M) {
  __shared__ float Asr[64][36];
  __shared__ float Asi[64][36];
  __shared__ float Ws1[32][64];
  __shared__ float Ws2[32][64];
  __shared__ float Wsm[32][64];
  const int t = threadIdx.x;
  const int r0 = blockIdx.x * 64;
  const int tc = t & 15, tr = t >> 4;
  const float* W0 = W;
  const float* W1 = W + (size_t)K * 64;
  const float* W2 = W + (size_t)2 * K * 64;
  float a1r[4][4] = {}, a1i[4][4] = {}, a2r[4][4] = {}, a2i[4][4] = {};
  float amr[4][4] = {}, ami[4][4] = {};
  for (int k0 = 0; k0 < K; k0 += 32) {
    for (int li = t; li < 512; li += 256) {  // A tiles: 64 rows x 8 f4
      int row = li >> 3, c4 = li & 7;
      int gr = r0 + row;
      float4 fr = make_float4(0.f, 0.f, 0.f, 0.f), fi = fr;
      if (gr < M) {
        fr = ld4(&Ar[(size_t)gr * K + k0 + c4 * 4]);
        fi = ld4(&Ai[(size_t)gr * K + k0 + c4 * 4]);
      }
      *reinterpret_cast<float4*>(&Asr[row][c4 * 4]) = fr;
      *reinterpret_cast<float4*>(&Asi[row][c4 * 4]) = fi;
    }
    for (int li = t; li < 512; li += 256) {  // W tiles: 32 rows x 16 f4
      int row = li >> 4, c4 = li & 15;
      size_t woff = (size_t)(k0 + row) * 64 + c4 * 4;
      float4 w1 = ld4(&W1[woff]);
      float4 w2 = ld4(&W2[woff]);
      float4 w0 = ld4(&W0[woff]);
      *reinterpret_cast<float4*>(&Ws1[row][c4 * 4]) = w1;
      *reinterpret_cast<float4*>(&Ws2[row][c4 * 4]) = w2;
      *reinterpret_cast<float4*>(&Wsm[row][c4 * 4]) =
          make_float4(w0.x - w2.x, w0.y - w2.y, w0.z - w2.z, w0.w - w2.w);
    }
    __syncthreads();
    for (int k = 0; k < 32; ++k) {
      float4 b1 = *reinterpret_cast<const float4*>(&Ws1[k][tc * 4]);
      float4 b2 = *reinterpret_cast<const float4*>(&Ws2[k][tc * 4]);
      float4 bm = *reinterpret_cast<const float4*>(&Wsm[k][tc * 4]);
#pragma unroll
      for (int i = 0; i < 4; ++i) {
        float ar = Asr[tr * 4 + i][k], ai = Asi[tr * 4 + i][k];
        a1r[i][0] += ar * b1.x; a1r[i][1] += ar * b1.y; a1r[i][2] += ar * b1.z; a1r[i][3] += ar * b1.w;
        a1i[i][0] += ai * b1.x; a1i[i][1] += ai * b1.y; a1i[i][2] += ai * b1.z; a1i[i][3] += ai * b1.w;
        a2r[i][0] += ar * b2.x; a2r[i][1] += ar * b2.y; a2r[i][2] += ar * b2.z; a2r[i][3] += ar * b2.w;
        a2i[i][0] += ai * b2.x; a2i[i][1] += ai * b2.y; a2i[i][2] += ai * b2.z; a2i[i][3] += ai * b2.w;
        amr[i][0] += ar * bm.x; amr[i][1] += ar * bm.y; amr[i][2] += ar * bm.z; amr[i][3] += ar * bm.w;
        ami[i][0] += ai * bm.x; ami[i][1] += ai * bm.y; ami[i][2] += ai * bm.z; ami[i][3] += ai * bm.w;
      }
    }
    __syncthreads();
  }
  float b0 = bias[tc * 4 + 0], bb1 = bias[tc * 4 + 1];
  float b2v = bias[tc * 4 + 2], b3 = bias[tc * 4 + 3];
#pragma unroll
  for (int i = 0; i < 4; ++i) {
    int gr = r0 + tr * 4 + i;
    if (gr >= M) continue;
    size_t pb = (size_t)gr * 256 + tc * 4;
    *reinterpret_cast<float4*>(&P[pb]) =
        make_float4(a1r[i][0], a1r[i][1], a1r[i][2], a1r[i][3]);
    *reinterpret_cast<float4*>(&P[pb + 64]) =
        make_float4(a1i[i][0], a1i[i][1], a1i[i][2], a1i[i][3]);
    *reinterpret_cast<float4*>(&P[pb + 128]) =
        make_float4(a2r[i][0], a2r[i][1], a2r[i][2], a2r[i][3]);
    *reinterpret_cast<float4*>(&P[pb + 192]) =
        make_float4(a2i[i][0], a2i[i][1], a2i[i][2], a2i[i][3]);
    size_t hb = (size_t)gr * 64 + tc * 4;
    *reinterpret_cast<float4*>(&Hr[hb]) =
        make_float4(amr[i][0] - ami[i][0] + b0, amr[i][1] - ami[i][1] + bb1,
                    amr[i][2] - ami[i][2] + b2v, amr[i][3] - ami[i][3] + b3);
    *reinterpret_cast<float4*>(&Hi[hb]) =
        make_float4(amr[i][0] + ami[i][0] + b0, amr[i][1] + ami[i][1] + bb1,
                    amr[i][2] + ami[i][2] + b2v, amr[i][3] + ami[i][3] + b3);
  }
}

// ---- gather A: H += T1, U = per-stream prop of g2 ---------------------------
// wave = 4 groups x 16 lanes; group g handles edges k0+g, k0+g+4, ...
__global__ __launch_bounds__(256) void k_gatherA(
    const float4* __restrict__ rec, const int* __restrict__ rp,
    const float* __restrict__ P, float* __restrict__ Hr, float* __restrict__ Hi,
    float* __restrict__ U, int N) {
  int d = blockIdx.x * 4 + (threadIdx.x >> 6);
  if (d >= N) return;
  int lane = threadIdx.x & 63;
  int g = lane >> 4, lg = lane & 15;
  float4 hr = {0, 0, 0, 0}, hi = hr, u0 = hr, u1 = hr, u2 = hr, u3 = hr;
  int k0 = rp[d], k1 = rp[d + 1];
#pragma unroll 2
  for (int k = k0 + g; k < k1; k += 4) {
    float4 r = rec[k];
    int s = __float_as_int(r.x);
    float cr = r.y, ci = r.z;
    const float* row = P + (size_t)s * 256 + lg * 4;
    float4 g1r = ld4(row), g1i = ld4(row + 64);
    float4 g2r = ld4(row + 128), g2i = ld4(row + 192);
    fmad4(hr, cr, g1r); fmad4(hr, -ci, g1i);
    fmad4(hi, ci, g1r); fmad4(hi, cr, g1i);
    fmad4(u0, cr, g2r); fmad4(u1, ci, g2i);
    fmad4(u2, ci, g2r); fmad4(u3, cr, g2i);
  }
  red4(hr); red4(hi); red4(u0); red4(u1); red4(u2); red4(u3);
  size_t hb = (size_t)d * 64 + lg * 4;
  size_t ub = (size_t)d * 256 + lg * 4;
  if (g == 0) {
    *reinterpret_cast<float4*>(&Hr[hb]) = add4(ld4(&Hr[hb]), hr);
    *reinterpret_cast<float4*>(&U[ub]) = u0;
  } else if (g == 1) {
    *reinterpret_cast<float4*>(&Hi[hb]) = add4(ld4(&Hi[hb]), hi);
    *reinterpret_cast<float4*>(&U[ub + 64]) = u1;
  } else if (g == 2) {
    *reinterpret_cast<float4*>(&U[ub + 128]) = u2;
  } else {
    *reinterpret_cast<float4*>(&U[ub + 192]) = u3;
  }
}

// ---- gather B: H += 2*prop(U), complex relu ---------------------------------
__global__ __launch_bounds__(256) void k_gatherB(
    const float4* __restrict__ rec, const int* __restrict__ rp,
    const float* __restrict__ U, float* __restrict__ Hr, float* __restrict__ Hi,
    int N) {
  int d = blockIdx.x * 4 + (threadIdx.x >> 6);
  if (d >= N) return;
  int lane = threadIdx.x & 63;
  int g = lane >> 4, lg = lane & 15;
  float4 hr = {0, 0, 0, 0}, hi = hr;
  int k0 = rp[d], k1 = rp[d + 1];
#pragma unroll 2
  for (int k = k0 + g; k < k1; k += 4) {
    float4 r = rec[k];
    int s = __float_as_int(r.x);
    float cr2 = 2.f * r.y, ci2 = 2.f * r.z;
    const float* row = U + (size_t)s * 256 + lg * 4;
    float4 u0 = ld4(row), u1 = ld4(row + 64);
    float4 u2 = ld4(row + 128), u3 = ld4(row + 192);
    fmad4(hr, cr2, u0); fmad4(hr, -ci2, u1);
    fmad4(hi, ci2, u2); fmad4(hi, cr2, u3);
  }
  red4(hr); red4(hi);
  if (g == 0) {
    size_t hb = (size_t)d * 64 + lg * 4;
    float4 fr = add4(ld4(&Hr[hb]), hr);
    float4 fi = add4(ld4(&Hi[hb]), hi);
    if (fr.x < 0.f) { fr.x = 0.f; fi.x = 0.f; }
    if (fr.y < 0.f) { fr.y = 0.f; fi.y = 0.f; }
    if (fr.z < 0.f) { fr.z = 0.f; fi.z = 0.f; }
    if (fr.w < 0.f) { fr.w = 0.f; fi.w = 0.f; }
    *reinterpret_cast<float4*>(&Hr[hb]) = fr;
    *reinterpret_cast<float4*>(&Hi[hb]) = fi;
  }
}

// ---- query gather + linear + log_softmax ------------------------------------
__global__ __launch_bounds__(256) void k_query(
    const int* __restrict__ qe, const float* __restrict__ xr,
    const float* __restrict__ xi, const float* __restrict__ Wlin,
    const float* __restrict__ blin, float* __restrict__ out, int Q) {
  int q = blockIdx.x * 4 + (threadIdx.x >> 6);
  if (q >= Q) return;
  int lane = threadIdx.x & 63;
  int q0 = qe[2 * q], q1 = qe[2 * q + 1];
  float x0 = xr[(size_t)q0 * 64 + lane];
  float x1 = xr[(size_t)q1 * 64 + lane];
  float x2 = xi[(size_t)q0 * 64 + lane];
  float x3 = xi[(size_t)q1 * 64 + lane];
  float l0 = x0 * Wlin[lane] + x1 * Wlin[64 + lane] + x2 * Wlin[128 + lane] + x3 * Wlin[192 + lane];
  float l1 = x0 * Wlin[256 + lane] + x1 * Wlin[320 + lane] + x2 * Wlin[384 + lane] + x3 * Wlin[448 + lane];
#pragma unroll
  for (int o = 32; o > 0; o >>= 1) {
    l0 += __shfl_xor(l0, o);
    l1 += __shfl_xor(l1, o);
  }
  if (lane == 0) {
    l0 += blin[0];
    l1 += blin[1];
    float m = fmaxf(l0, l1);
    float lse = m + logf(expf(l0 - m) + expf(l1 - m));
    out[2 * q + 0] = l0 - lse;
    out[2 * q + 1] = l1 - lse;
  }
}

extern "C" void kernel_launch(void* const* d_in, const int* in_sizes, int n_in,
                              void* d_out, int out_size, void* d_ws, size_t ws_size,
                              hipStream_t stream) {
  const float* real = (const float*)d_in[0];
  const float* imag = (const float*)d_in[1];
  const int* ei     = (const int*)d_in[2];
  const int* qe     = (const int*)d_in[3];
  const float* ew   = (const float*)d_in[4];
  const float* W1   = (const float*)d_in[5];
  const float* b1   = (const float*)d_in[6];
  const float* W2   = (const float*)d_in[7];
  const float* b2   = (const float*)d_in[8];
  const float* Wlin = (const float*)d_in[9];
  const float* blin = (const float*)d_in[10];

  const int N = in_sizes[0] / 128;
  const int E = in_sizes[4];
  const int Q = in_sizes[3] / 2;
  const int* u = ei;
  const int* v = ei + E;

  float* ws = (float*)d_ws;
  size_t off = 0;
  auto alloc = [&](size_t n) { float* p = ws + off; off += n; return p; };
  const size_t N64 = (size_t)N * 64;
  const size_t N256 = (size_t)N * 256;

  float4* rec = (float4*)alloc((size_t)2 * E * 4);   // 16B-aligned first
  float* P   = alloc(N256);
  float* U   = alloc(N256);
  float* HAr = alloc(N64);
  float* HAi = alloc(N64);
  float* HBr = alloc(N64);
  float* HBi = alloc(N64);
  float* deg = alloc(N);
  int* cnt  = (int*)alloc(N);
  int* rp   = (int*)alloc(N + 1);
  int* nxt  = (int*)alloc(N);
  int* bsum = (int*)alloc(64);
  (void)ws_size; (void)n_in; (void)out_size;

  const int eb = (E + 255) / 256;
  const int mb = (N + 63) / 64;
  const int NB = (N + 1023) / 1024;
  const int gb = (N + 3) / 4;

  // --- graph structure + coefficients ---
  hipMemsetAsync(deg, 0, (size_t)N * sizeof(float), stream);
  hipMemsetAsync(cnt, 0, (size_t)N * sizeof(int), stream);
  k_deg_count<<<eb, 256, 0, stream>>>(u, v, ew, deg, cnt, E);
  k_scan1<<<NB, 256, 0, stream>>>(cnt, rp, bsum, N);
  k_scan2<<<1, 64, 0, stream>>>(bsum, NB);
  k_scan3<<<(N + 256) / 256, 256, 0, stream>>>(rp, nxt, bsum, N, 2 * E);
  k_scatter<<<eb, 256, 0, stream>>>(u, v, ew, deg, nxt, rec, E);

  // --- layer 1 (K=128) ---
  k_gemmF<128><<<mb, 256, 0, stream>>>(real, imag, W1, b1, P, HAr, HAi, N);
  k_gatherA<<<gb, 256, 0, stream>>>(rec, rp, P, HAr, HAi, U, N);
  k_gatherB<<<gb, 256, 0, stream>>>(rec, rp, U, HAr, HAi, N);

  // --- layer 2 (K=64) ---
  k_gemmF<64><<<mb, 256, 0, stream>>>(HAr, HAi, W2, b2, P, HBr, HBi, N);
  k_gatherA<<<gb, 256, 0, stream>>>(rec, rp, P, HBr, HBi, U, N);
  k_gatherB<<<gb, 256, 0, stream>>>(rec, rp, U, HBr, HBi, N);

  // --- queries ---
  k_query<<<(Q + 3) / 4, 256, 0, stream>>>(qe, HBr, HBi, Wlin, blin, (float*)d_out, Q);
}

// Round 6
// 892.189 us; speedup vs baseline: 1.0143x; 1.0143x over previous
//
#include <hip/hip_runtime.h>

// ---------------------------------------------------------------------------
// MagNet link prediction forward, f32 (16-bit quant of propagated streams
// fails: complex-ReLU mask flips amplify tiny hr errors — rounds 3/4).
// Gather (CSR) formulation with HALF-FOOTPRINT split passes: each sparse pass
// streams one 25.6MB array of 512B rows (vs 51MB/1KB rows in round 5, which
// ran at 51% cache absorption). Feature-pair interleaved layouts give clean
// algebraic splits:
//   P1[n][128] = (g1r|g1i) pairs, P2[n][128] = (g2r|g2i) pairs (g=x@W1,x@W2)
//   U1[n][128] = (u0|u1) pairs,   U2[n][128] = (u2|u3) pairs
//   A1: hr += cr*g1r - ci*g1i ; hi += ci*g1r + cr*g1i          (reads P1)
//   A2: u0=Σcr*g2r u1=Σci*g2i u2=Σci*g2r u3=Σcr*g2i            (reads P2)
//   B1: hr += 2(cr*u0 - ci*u1)                                  (reads U1)
//   B2: hi += 2(ci*u2 + cr*u3), then complex ReLU on (hr,hi)    (reads U2)
// Wave = 2 groups x 32 lanes; group g owns edges k0+g, k0+g+2, ...; lane
// reads one float4 (2 feature pairs); xor-32 shuffle combines groups.
// Reverse edges reuse forward coefficients with ni -> -ni.
// ---------------------------------------------------------------------------

__device__ __forceinline__ float4 ld4(const float* __restrict__ p) {
  return *reinterpret_cast<const float4*>(p);
}
__device__ __forceinline__ float2 ld2(const float* __restrict__ p) {
  return *reinterpret_cast<const float2*>(p);
}

// ---- degree (0.5*w per endpoint) + incident-edge count ----------------------
__global__ void k_deg_count(const int* __restrict__ u, const int* __restrict__ v,
                            const float* __restrict__ w, float* __restrict__ deg,
                            int* __restrict__ cnt, int E) {
  int e = blockIdx.x * 256 + threadIdx.x;
  if (e >= E) return;
  float hw = 0.5f * w[e];
  int a = u[e], b = v[e];
  unsafeAtomicAdd(&deg[a], hw);
  unsafeAtomicAdd(&deg[b], hw);
  atomicAdd(&cnt[a], 1);
  atomicAdd(&cnt[b], 1);
}

// ---- exclusive scan of cnt[N] -> rp ----------------------------------------
__global__ __launch_bounds__(256) void k_scan1(const int* __restrict__ cnt,
                                               int* __restrict__ rp,
                                               int* __restrict__ bsum, int N) {
  __shared__ int sh[256];
  int t = threadIdx.x;
  int base = blockIdx.x * 1024 + t * 4;
  int c0 = (base + 0 < N) ? cnt[base + 0] : 0;
  int c1 = (base + 1 < N) ? cnt[base + 1] : 0;
  int c2 = (base + 2 < N) ? cnt[base + 2] : 0;
  int c3 = (base + 3 < N) ? cnt[base + 3] : 0;
  int s = c0 + c1 + c2 + c3;
  sh[t] = s;
  __syncthreads();
  for (int o = 1; o < 256; o <<= 1) {
    int y = (t >= o) ? sh[t - o] : 0;
    __syncthreads();
    if (t >= o) sh[t] += y;
    __syncthreads();
  }
  int excl = sh[t] - s;
  if (base + 0 < N) rp[base + 0] = excl;
  if (base + 1 < N) rp[base + 1] = excl + c0;
  if (base + 2 < N) rp[base + 2] = excl + c0 + c1;
  if (base + 3 < N) rp[base + 3] = excl + c0 + c1 + c2;
  if (t == 255) bsum[blockIdx.x] = sh[255];
}

__global__ void k_scan2(int* __restrict__ bsum, int NB) {
  if (threadIdx.x == 0 && blockIdx.x == 0) {
    int run = 0;
    for (int i = 0; i < NB; ++i) { int x = bsum[i]; bsum[i] = run; run += x; }
  }
}

__global__ void k_scan3(int* __restrict__ rp, int* __restrict__ nxt,
                        const int* __restrict__ bsum, int N, int twoE) {
  int i = blockIdx.x * 256 + threadIdx.x;
  if (i < N) {
    int val = rp[i] + bsum[i >> 10];
    rp[i] = val;
    nxt[i] = val;
  } else if (i == N) {
    rp[N] = twoE;
  }
}

// ---- scatter edge records: src[pos], cf[pos]=(cr,ci) ------------------------
__global__ void k_scatter(const int* __restrict__ u, const int* __restrict__ v,
                          const float* __restrict__ w, const float* __restrict__ deg,
                          int* __restrict__ nxt, int* __restrict__ src,
                          float2* __restrict__ cf, int E) {
  int e = blockIdx.x * 256 + threadIdx.x;
  if (e >= E) return;
  int a = u[e], b = v[e];
  float we = w[e];
  float da = deg[a], db = deg[b];
  float ia = da > 0.f ? rsqrtf(da) : 0.f;
  float ib = db > 0.f ? rsqrtf(db) : 0.f;
  float norm = ia * (0.5f * we) * ib;
  float th = 1.57079632679489662f * we;  // 2*pi*q*w, q=0.25
  float sn, cs;
  sincosf(th, &sn, &cs);
  float cr = -norm * cs, ci = -norm * sn;
  int p1 = atomicAdd(&nxt[b], 1);  // forward a->b, coeff (cr, ci)
  src[p1] = a;
  cf[p1] = make_float2(cr, ci);
  int p2 = atomicAdd(&nxt[a], 1);  // reverse b->a, coeff (cr, -ci)
  src[p2] = b;
  cf[p2] = make_float2(cr, -ci);
}

// ---- fused 6-stream GEMM: interleaved P1/P2 rows + biased H base ------------
template <int K>
__global__ __launch_bounds__(256) void k_gemmF(
    const float* __restrict__ Ar, const float* __restrict__ Ai,
    const float* __restrict__ W,  // [3][K][64]
    const float* __restrict__ bias,
    float* __restrict__ P1, float* __restrict__ P2,
    float* __restrict__ Hr, float* __restrict__ Hi, int M) {
  __shared__ float Asr[64][36];
  __shared__ float Asi[64][36];
  __shared__ float Ws1[32][64];
  __shared__ float Ws2[32][64];
  __shared__ float Wsm[32][64];
  const int t = threadIdx.x;
  const int r0 = blockIdx.x * 64;
  const int tc = t & 15, tr = t >> 4;
  const float* W0 = W;
  const float* W1 = W + (size_t)K * 64;
  const float* W2 = W + (size_t)2 * K * 64;
  float a1r[4][4] = {}, a1i[4][4] = {}, a2r[4][4] = {}, a2i[4][4] = {};
  float amr[4][4] = {}, ami[4][4] = {};
  for (int k0 = 0; k0 < K; k0 += 32) {
    for (int li = t; li < 512; li += 256) {  // A tiles: 64 rows x 8 f4
      int row = li >> 3, c4 = li & 7;
      int gr = r0 + row;
      float4 fr = make_float4(0.f, 0.f, 0.f, 0.f), fi = fr;
      if (gr < M) {
        fr = ld4(&Ar[(size_t)gr * K + k0 + c4 * 4]);
        fi = ld4(&Ai[(size_t)gr * K + k0 + c4 * 4]);
      }
      *reinterpret_cast<float4*>(&Asr[row][c4 * 4]) = fr;
      *reinterpret_cast<float4*>(&Asi[row][c4 * 4]) = fi;
    }
    for (int li = t; li < 512; li += 256) {  // W tiles: 32 rows x 16 f4
      int row = li >> 4, c4 = li & 15;
      size_t woff = (size_t)(k0 + row) * 64 + c4 * 4;
      float4 w1 = ld4(&W1[woff]);
      float4 w2 = ld4(&W2[woff]);
      float4 w0 = ld4(&W0[woff]);
      *reinterpret_cast<float4*>(&Ws1[row][c4 * 4]) = w1;
      *reinterpret_cast<float4*>(&Ws2[row][c4 * 4]) = w2;
      *reinterpret_cast<float4*>(&Wsm[row][c4 * 4]) =
          make_float4(w0.x - w2.x, w0.y - w2.y, w0.z - w2.z, w0.w - w2.w);
    }
    __syncthreads();
    for (int k = 0; k < 32; ++k) {
      float4 b1 = *reinterpret_cast<const float4*>(&Ws1[k][tc * 4]);
      float4 b2 = *reinterpret_cast<const float4*>(&Ws2[k][tc * 4]);
      float4 bm = *reinterpret_cast<const float4*>(&Wsm[k][tc * 4]);
#pragma unroll
      for (int i = 0; i < 4; ++i) {
        float ar = Asr[tr * 4 + i][k], ai = Asi[tr * 4 + i][k];
        a1r[i][0] += ar * b1.x; a1r[i][1] += ar * b1.y; a1r[i][2] += ar * b1.z; a1r[i][3] += ar * b1.w;
        a1i[i][0] += ai * b1.x; a1i[i][1] += ai * b1.y; a1i[i][2] += ai * b1.z; a1i[i][3] += ai * b1.w;
        a2r[i][0] += ar * b2.x; a2r[i][1] += ar * b2.y; a2r[i][2] += ar * b2.z; a2r[i][3] += ar * b2.w;
        a2i[i][0] += ai * b2.x; a2i[i][1] += ai * b2.y; a2i[i][2] += ai * b2.z; a2i[i][3] += ai * b2.w;
        amr[i][0] += ar * bm.x; amr[i][1] += ar * bm.y; amr[i][2] += ar * bm.z; amr[i][3] += ar * bm.w;
        ami[i][0] += ai * bm.x; ami[i][1] += ai * bm.y; ami[i][2] += ai * bm.z; ami[i][3] += ai * bm.w;
      }
    }
    __syncthreads();
  }
  float b0 = bias[tc * 4 + 0], bb1 = bias[tc * 4 + 1];
  float b2v = bias[tc * 4 + 2], b3 = bias[tc * 4 + 3];
#pragma unroll
  for (int i = 0; i < 4; ++i) {
    int gr = r0 + tr * 4 + i;
    if (gr >= M) continue;
    size_t pb = (size_t)gr * 128 + tc * 8;  // feature pairs: f=4tc..4tc+3
    *reinterpret_cast<float4*>(&P1[pb]) =
        make_float4(a1r[i][0], a1i[i][0], a1r[i][1], a1i[i][1]);
    *reinterpret_cast<float4*>(&P1[pb + 4]) =
        make_float4(a1r[i][2], a1i[i][2], a1r[i][3], a1i[i][3]);
    *reinterpret_cast<float4*>(&P2[pb]) =
        make_float4(a2r[i][0], a2i[i][0], a2r[i][1], a2i[i][1]);
    *reinterpret_cast<float4*>(&P2[pb + 4]) =
        make_float4(a2r[i][2], a2i[i][2], a2r[i][3], a2i[i][3]);
    size_t hb = (size_t)gr * 64 + tc * 4;
    *reinterpret_cast<float4*>(&Hr[hb]) =
        make_float4(amr[i][0] - ami[i][0] + b0, amr[i][1] - ami[i][1] + bb1,
                    amr[i][2] - ami[i][2] + b2v, amr[i][3] - ami[i][3] + b3);
    *reinterpret_cast<float4*>(&Hi[hb]) =
        make_float4(amr[i][0] + ami[i][0] + b0, amr[i][1] + ami[i][1] + bb1,
                    amr[i][2] + ami[i][2] + b2v, amr[i][3] + ami[i][3] + b3);
  }
}

// ---- A1: hr/hi += T1 (reads P1: (g1r,g1i) pairs) ----------------------------
__global__ __launch_bounds__(256) void k_gA1(
    const int* __restrict__ src, const float2* __restrict__ cf,
    const int* __restrict__ rp, const float* __restrict__ P1,
    float* __restrict__ Hr, float* __restrict__ Hi, int N) {
  int d = blockIdx.x * 4 + (threadIdx.x >> 6);
  if (d >= N) return;
  int lane = threadIdx.x & 63;
  int g = lane >> 5, lg = lane & 31;
  float4 acc = {0, 0, 0, 0};  // hr0, hi0, hr1, hi1
  int k1 = rp[d + 1];
#pragma unroll 2
  for (int k = rp[d] + g; k < k1; k += 2) {
    int s = src[k];
    float2 c = cf[k];
    float4 v = ld4(P1 + (size_t)s * 128 + lg * 4);
    acc.x += c.x * v.x - c.y * v.y;
    acc.y += c.y * v.x + c.x * v.y;
    acc.z += c.x * v.z - c.y * v.w;
    acc.w += c.y * v.z + c.x * v.w;
  }
  acc.x += __shfl_xor(acc.x, 32);
  acc.y += __shfl_xor(acc.y, 32);
  acc.z += __shfl_xor(acc.z, 32);
  acc.w += __shfl_xor(acc.w, 32);
  size_t hb = (size_t)d * 64 + lg * 2;
  if (g == 0) {
    float2 h = ld2(&Hr[hb]);
    *reinterpret_cast<float2*>(&Hr[hb]) = make_float2(h.x + acc.x, h.y + acc.z);
  } else {
    float2 h = ld2(&Hi[hb]);
    *reinterpret_cast<float2*>(&Hi[hb]) = make_float2(h.x + acc.y, h.y + acc.w);
  }
}

// ---- A2: U1/U2 = per-stream prop of g2 (reads P2: (g2r,g2i) pairs) ----------
__global__ __launch_bounds__(256) void k_gA2(
    const int* __restrict__ src, const float2* __restrict__ cf,
    const int* __restrict__ rp, const float* __restrict__ P2,
    float* __restrict__ U1, float* __restrict__ U2, int N) {
  int d = blockIdx.x * 4 + (threadIdx.x >> 6);
  if (d >= N) return;
  int lane = threadIdx.x & 63;
  int g = lane >> 5, lg = lane & 31;
  float4 a01 = {0, 0, 0, 0};  // u0_0, u1_0, u0_1, u1_1
  float4 a23 = {0, 0, 0, 0};  // u2_0, u3_0, u2_1, u3_1
  int k1 = rp[d + 1];
#pragma unroll 2
  for (int k = rp[d] + g; k < k1; k += 2) {
    int s = src[k];
    float2 c = cf[k];
    float4 v = ld4(P2 + (size_t)s * 128 + lg * 4);
    a01.x += c.x * v.x; a01.y += c.y * v.y;
    a01.z += c.x * v.z; a01.w += c.y * v.w;
    a23.x += c.y * v.x; a23.y += c.x * v.y;
    a23.z += c.y * v.z; a23.w += c.x * v.w;
  }
  a01.x += __shfl_xor(a01.x, 32); a01.y += __shfl_xor(a01.y, 32);
  a01.z += __shfl_xor(a01.z, 32); a01.w += __shfl_xor(a01.w, 32);
  a23.x += __shfl_xor(a23.x, 32); a23.y += __shfl_xor(a23.y, 32);
  a23.z += __shfl_xor(a23.z, 32); a23.w += __shfl_xor(a23.w, 32);
  size_t ub = (size_t)d * 128 + lg * 4;
  if (g == 0)
    *reinterpret_cast<float4*>(&U1[ub]) = a01;
  else
    *reinterpret_cast<float4*>(&U2[ub]) = a23;
}

// ---- B1: hr += 2(cr*u0 - ci*u1) (reads U1) ----------------------------------
__global__ __launch_bounds__(256) void k_gB1(
    const int* __restrict__ src, const float2* __restrict__ cf,
    const int* __restrict__ rp, const float* __restrict__ U1,
    float* __restrict__ Hr, int N) {
  int d = blockIdx.x * 4 + (threadIdx.x >> 6);
  if (d >= N) return;
  int lane = threadIdx.x & 63;
  int g = lane >> 5, lg = lane & 31;
  float2 acc = {0, 0};
  int k1 = rp[d + 1];
#pragma unroll 2
  for (int k = rp[d] + g; k < k1; k += 2) {
    int s = src[k];
    float2 c = cf[k];
    float4 v = ld4(U1 + (size_t)s * 128 + lg * 4);
    acc.x += c.x * v.x - c.y * v.y;
    acc.y += c.x * v.z - c.y * v.w;
  }
  acc.x += __shfl_xor(acc.x, 32);
  acc.y += __shfl_xor(acc.y, 32);
  if (g == 0) {
    size_t hb = (size_t)d * 64 + lg * 2;
    float2 h = ld2(&Hr[hb]);
    *reinterpret_cast<float2*>(&Hr[hb]) =
        make_float2(h.x + 2.f * acc.x, h.y + 2.f * acc.y);
  }
}

// ---- B2: hi += 2(ci*u2 + cr*u3), complex ReLU (reads U2, final Hr) ----------
__global__ __launch_bounds__(256) void k_gB2(
    const int* __restrict__ src, const float2* __restrict__ cf,
    const int* __restrict__ rp, const float* __restrict__ U2,
    float* __restrict__ Hr, float* __restrict__ Hi, int N) {
  int d = blockIdx.x * 4 + (threadIdx.x >> 6);
  if (d >= N) return;
  int lane = threadIdx.x & 63;
  int g = lane >> 5, lg = lane & 31;
  float2 acc = {0, 0};
  int k1 = rp[d + 1];
#pragma unroll 2
  for (int k = rp[d] + g; k < k1; k += 2) {
    int s = src[k];
    float2 c = cf[k];
    float4 v = ld4(U2 + (size_t)s * 128 + lg * 4);
    acc.x += c.y * v.x + c.x * v.y;
    acc.y += c.y * v.z + c.x * v.w;
  }
  acc.x += __shfl_xor(acc.x, 32);
  acc.y += __shfl_xor(acc.y, 32);
  if (g == 0) {
    size_t hb = (size_t)d * 64 + lg * 2;
    float2 hr = ld2(&Hr[hb]);
    float2 hi = ld2(&Hi[hb]);
    hi.x += 2.f * acc.x;
    hi.y += 2.f * acc.y;
    if (hr.x < 0.f) { hr.x = 0.f; hi.x = 0.f; }
    if (hr.y < 0.f) { hr.y = 0.f; hi.y = 0.f; }
    *reinterpret_cast<float2*>(&Hr[hb]) = hr;
    *reinterpret_cast<float2*>(&Hi[hb]) = hi;
  }
}

// ---- query gather + linear + log_softmax ------------------------------------
__global__ __launch_bounds__(256) void k_query(
    const int* __restrict__ qe, const float* __restrict__ xr,
    const float* __restrict__ xi, const float* __restrict__ Wlin,
    const float* __restrict__ blin, float* __restrict__ out, int Q) {
  int q = blockIdx.x * 4 + (threadIdx.x >> 6);
  if (q >= Q) return;
  int lane = threadIdx.x & 63;
  int q0 = qe[2 * q], q1 = qe[2 * q + 1];
  float x0 = xr[(size_t)q0 * 64 + lane];
  float x1 = xr[(size_t)q1 * 64 + lane];
  float x2 = xi[(size_t)q0 * 64 + lane];
  float x3 = xi[(size_t)q1 * 64 + lane];
  float l0 = x0 * Wlin[lane] + x1 * Wlin[64 + lane] + x2 * Wlin[128 + lane] + x3 * Wlin[192 + lane];
  float l1 = x0 * Wlin[256 + lane] + x1 * Wlin[320 + lane] + x2 * Wlin[384 + lane] + x3 * Wlin[448 + lane];
#pragma unroll
  for (int o = 32; o > 0; o >>= 1) {
    l0 += __shfl_xor(l0, o);
    l1 += __shfl_xor(l1, o);
  }
  if (lane == 0) {
    l0 += blin[0];
    l1 += blin[1];
    float m = fmaxf(l0, l1);
    float lse = m + logf(expf(l0 - m) + expf(l1 - m));
    out[2 * q + 0] = l0 - lse;
    out[2 * q + 1] = l1 - lse;
  }
}

extern "C" void kernel_launch(void* const* d_in, const int* in_sizes, int n_in,
                              void* d_out, int out_size, void* d_ws, size_t ws_size,
                              hipStream_t stream) {
  const float* real = (const float*)d_in[0];
  const float* imag = (const float*)d_in[1];
  const int* ei     = (const int*)d_in[2];
  const int* qe     = (const int*)d_in[3];
  const float* ew   = (const float*)d_in[4];
  const float* W1   = (const float*)d_in[5];
  const float* b1   = (const float*)d_in[6];
  const float* W2   = (const float*)d_in[7];
  const float* b2   = (const float*)d_in[8];
  const float* Wlin = (const float*)d_in[9];
  const float* blin = (const float*)d_in[10];

  const int N = in_sizes[0] / 128;
  const int E = in_sizes[4];
  const int Q = in_sizes[3] / 2;
  const int* u = ei;
  const int* v = ei + E;

  float* ws = (float*)d_ws;
  size_t off = 0;
  auto alloc = [&](size_t n) { float* p = ws + off; off += n; return p; };
  const size_t N64 = (size_t)N * 64;
  const size_t N128 = (size_t)N * 128;

  float2* cf = (float2*)alloc((size_t)2 * E * 2);  // 8B-aligned (first)
  int* src  = (int*)alloc((size_t)2 * E);
  float* P1  = alloc(N128);
  float* P2  = alloc(N128);
  float* U1  = alloc(N128);
  float* U2  = alloc(N128);
  float* HAr = alloc(N64);
  float* HAi = alloc(N64);
  float* HBr = alloc(N64);
  float* HBi = alloc(N64);
  float* deg = alloc(N);
  int* cnt  = (int*)alloc(N);
  int* rp   = (int*)alloc(N + 1);
  int* nxt  = (int*)alloc(N);
  int* bsum = (int*)alloc(64);
  (void)ws_size; (void)n_in; (void)out_size;

  const int eb = (E + 255) / 256;
  const int mb = (N + 63) / 64;
  const int NB = (N + 1023) / 1024;
  const int gb = (N + 3) / 4;

  // --- graph structure + coefficients ---
  hipMemsetAsync(deg, 0, (size_t)N * sizeof(float), stream);
  hipMemsetAsync(cnt, 0, (size_t)N * sizeof(int), stream);
  k_deg_count<<<eb, 256, 0, stream>>>(u, v, ew, deg, cnt, E);
  k_scan1<<<NB, 256, 0, stream>>>(cnt, rp, bsum, N);
  k_scan2<<<1, 64, 0, stream>>>(bsum, NB);
  k_scan3<<<(N + 256) / 256, 256, 0, stream>>>(rp, nxt, bsum, N, 2 * E);
  k_scatter<<<eb, 256, 0, stream>>>(u, v, ew, deg, nxt, src, cf, E);

  // --- layer 1 (K=128) ---
  k_gemmF<128><<<mb, 256, 0, stream>>>(real, imag, W1, b1, P1, P2, HAr, HAi, N);
  k_gA1<<<gb, 256, 0, stream>>>(src, cf, rp, P1, HAr, HAi, N);
  k_gA2<<<gb, 256, 0, stream>>>(src, cf, rp, P2, U1, U2, N);
  k_gB1<<<gb, 256, 0, stream>>>(src, cf, rp, U1, HAr, N);
  k_gB2<<<gb, 256, 0, stream>>>(src, cf, rp, U2, HAr, HAi, N);

  // --- layer 2 (K=64) ---
  k_gemmF<64><<<mb, 256, 0, stream>>>(HAr, HAi, W2, b2, P1, P2, HBr, HBi, N);
  k_gA1<<<gb, 256, 0, stream>>>(src, cf, rp, P1, HBr, HBi, N);
  k_gA2<<<gb, 256, 0, stream>>>(src, cf, rp, P2, U1, U2, N);
  k_gB1<<<gb, 256, 0, stream>>>(src, cf, rp, U1, HBr, N);
  k_gB2<<<gb, 256, 0, stream>>>(src, cf, rp, U2, HBr, HBi, N);

  // --- queries ---
  k_query<<<(Q + 3) / 4, 256, 0, stream>>>(qe, HBr, HBi, Wlin, blin, (float*)d_out, Q);
}

// Round 7
// 888.242 us; speedup vs baseline: 1.0188x; 1.0044x over previous
//
#include <hip/hip_runtime.h>

// ---------------------------------------------------------------------------
// MagNet link prediction forward, f32 (16-bit quant of propagated streams
// fails: complex-ReLU mask flips amplify tiny hr errors — rounds 3/4).
// Gather (CSR) formulation, split half-footprint sparse passes (round 6).
// Round 7: (a) deg+cnt fused into ONE 64-bit atomic (cnt<<32 | fx24(0.5w)) —
// memory-side atomic transactions halved; (b) GEMM reads W directly from
// global (L1/L2 broadcast) instead of LDS, BM=32 tile -> 1563 blocks,
// 9.2KB LDS -> occupancy-bound fixed.
//   P1[n][128] = (g1r|g1i) pairs, P2[n][128] = (g2r|g2i) pairs
//   A1: hr += cr*g1r - ci*g1i ; hi += ci*g1r + cr*g1i          (reads P1)
//   A2: u0=Σcr*g2r u1=Σci*g2i u2=Σci*g2r u3=Σcr*g2i            (reads P2)
//   B1: hr += 2(cr*u0 - ci*u1)                                  (reads U1)
//   B2: hi += 2(ci*u2 + cr*u3), then complex ReLU on (hr,hi)    (reads U2)
// Reverse edges reuse forward coefficients with ni -> -ni.
// ---------------------------------------------------------------------------

__device__ __forceinline__ float4 ld4(const float* __restrict__ p) {
  return *reinterpret_cast<const float4*>(p);
}
__device__ __forceinline__ float2 ld2(const float* __restrict__ p) {
  return *reinterpret_cast<const float2*>(p);
}

// ---- degree+count in one packed 64-bit atomic -------------------------------
__global__ void k_deg_count(const int* __restrict__ u, const int* __restrict__ v,
                            const float* __restrict__ w,
                            unsigned long long* __restrict__ dc, int E) {
  int e = blockIdx.x * 256 + threadIdx.x;
  if (e >= E) return;
  float hw = 0.5f * w[e];
  unsigned fx = __float2uint_rn(hw * 16777216.f);  // 2^24 fixed point
  unsigned long long pk = (1ULL << 32) | (unsigned long long)fx;
  atomicAdd(&dc[u[e]], pk);
  atomicAdd(&dc[v[e]], pk);
}

// ---- exclusive scan of cnt (= dc>>32) -> rp ---------------------------------
__global__ __launch_bounds__(256) void k_scan1(
    const unsigned long long* __restrict__ dc, int* __restrict__ rp,
    int* __restrict__ bsum, int N) {
  __shared__ int sh[256];
  int t = threadIdx.x;
  int base = blockIdx.x * 1024 + t * 4;
  int c0 = (base + 0 < N) ? (int)(dc[base + 0] >> 32) : 0;
  int c1 = (base + 1 < N) ? (int)(dc[base + 1] >> 32) : 0;
  int c2 = (base + 2 < N) ? (int)(dc[base + 2] >> 32) : 0;
  int c3 = (base + 3 < N) ? (int)(dc[base + 3] >> 32) : 0;
  int s = c0 + c1 + c2 + c3;
  sh[t] = s;
  __syncthreads();
  for (int o = 1; o < 256; o <<= 1) {
    int y = (t >= o) ? sh[t - o] : 0;
    __syncthreads();
    if (t >= o) sh[t] += y;
    __syncthreads();
  }
  int excl = sh[t] - s;
  if (base + 0 < N) rp[base + 0] = excl;
  if (base + 1 < N) rp[base + 1] = excl + c0;
  if (base + 2 < N) rp[base + 2] = excl + c0 + c1;
  if (base + 3 < N) rp[base + 3] = excl + c0 + c1 + c2;
  if (t == 255) bsum[blockIdx.x] = sh[255];
}

__global__ void k_scan2(int* __restrict__ bsum, int NB) {
  if (threadIdx.x == 0 && blockIdx.x == 0) {
    int run = 0;
    for (int i = 0; i < NB; ++i) { int x = bsum[i]; bsum[i] = run; run += x; }
  }
}

__global__ void k_scan3(int* __restrict__ rp, int* __restrict__ nxt,
                        const int* __restrict__ bsum, int N, int twoE) {
  int i = blockIdx.x * 256 + threadIdx.x;
  if (i < N) {
    int val = rp[i] + bsum[i >> 10];
    rp[i] = val;
    nxt[i] = val;
  } else if (i == N) {
    rp[N] = twoE;
  }
}

// ---- scatter edge records: src[pos], cf[pos]=(cr,ci) ------------------------
__global__ void k_scatter(const int* __restrict__ u, const int* __restrict__ v,
                          const float* __restrict__ w,
                          const unsigned long long* __restrict__ dc,
                          int* __restrict__ nxt, int* __restrict__ src,
                          float2* __restrict__ cf, int E) {
  int e = blockIdx.x * 256 + threadIdx.x;
  if (e >= E) return;
  int a = u[e], b = v[e];
  float we = w[e];
  float da = (float)(unsigned)dc[a] * (1.f / 16777216.f);
  float db = (float)(unsigned)dc[b] * (1.f / 16777216.f);
  float ia = da > 0.f ? rsqrtf(da) : 0.f;
  float ib = db > 0.f ? rsqrtf(db) : 0.f;
  float norm = ia * (0.5f * we) * ib;
  float th = 1.57079632679489662f * we;  // 2*pi*q*w, q=0.25
  float sn, cs;
  sincosf(th, &sn, &cs);
  float cr = -norm * cs, ci = -norm * sn;
  int p1 = atomicAdd(&nxt[b], 1);  // forward a->b, coeff (cr, ci)
  src[p1] = a;
  cf[p1] = make_float2(cr, ci);
  int p2 = atomicAdd(&nxt[a], 1);  // reverse b->a, coeff (cr, -ci)
  src[p2] = b;
  cf[p2] = make_float2(cr, -ci);
}

// ---- fused 6-stream GEMM: BM=32 tile, A in LDS, W from global (L1/L2) ------
template <int K>
__global__ __launch_bounds__(256) void k_gemmF(
    const float* __restrict__ Ar, const float* __restrict__ Ai,
    const float* __restrict__ W,  // [3][K][64]
    const float* __restrict__ bias,
    float* __restrict__ P1, float* __restrict__ P2,
    float* __restrict__ Hr, float* __restrict__ Hi, int M) {
  __shared__ float Asr[32][36];
  __shared__ float Asi[32][36];
  const int t = threadIdx.x;
  const int r0 = blockIdx.x * 32;
  const int tc = t & 15, tr = t >> 4;
  const float* W0 = W;
  const float* W1 = W + (size_t)K * 64;
  const float* W2 = W + (size_t)2 * K * 64;
  float a1r[2][4] = {}, a1i[2][4] = {}, a2r[2][4] = {}, a2i[2][4] = {};
  float amr[2][4] = {}, ami[2][4] = {};
  for (int k0 = 0; k0 < K; k0 += 32) {
    {  // stage A tile: 32 rows x 32 k, one float4 per thread per array
      int row = t >> 3, c4 = t & 7;
      int gr = r0 + row;
      float4 fr = make_float4(0.f, 0.f, 0.f, 0.f), fi = fr;
      if (gr < M) {
        fr = ld4(&Ar[(size_t)gr * K + k0 + c4 * 4]);
        fi = ld4(&Ai[(size_t)gr * K + k0 + c4 * 4]);
      }
      *reinterpret_cast<float4*>(&Asr[row][c4 * 4]) = fr;
      *reinterpret_cast<float4*>(&Asi[row][c4 * 4]) = fi;
    }
    __syncthreads();
#pragma unroll 4
    for (int k = 0; k < 32; ++k) {
      size_t wo = (size_t)(k0 + k) * 64 + tc * 4;
      float4 b1 = ld4(&W1[wo]);
      float4 b2 = ld4(&W2[wo]);
      float4 w0 = ld4(&W0[wo]);
      float4 bm = make_float4(w0.x - b2.x, w0.y - b2.y, w0.z - b2.z, w0.w - b2.w);
#pragma unroll
      for (int i = 0; i < 2; ++i) {
        float ar = Asr[tr * 2 + i][k], ai = Asi[tr * 2 + i][k];
        a1r[i][0] += ar * b1.x; a1r[i][1] += ar * b1.y; a1r[i][2] += ar * b1.z; a1r[i][3] += ar * b1.w;
        a1i[i][0] += ai * b1.x; a1i[i][1] += ai * b1.y; a1i[i][2] += ai * b1.z; a1i[i][3] += ai * b1.w;
        a2r[i][0] += ar * b2.x; a2r[i][1] += ar * b2.y; a2r[i][2] += ar * b2.z; a2r[i][3] += ar * b2.w;
        a2i[i][0] += ai * b2.x; a2i[i][1] += ai * b2.y; a2i[i][2] += ai * b2.z; a2i[i][3] += ai * b2.w;
        amr[i][0] += ar * bm.x; amr[i][1] += ar * bm.y; amr[i][2] += ar * bm.z; amr[i][3] += ar * bm.w;
        ami[i][0] += ai * bm.x; ami[i][1] += ai * bm.y; ami[i][2] += ai * bm.z; ami[i][3] += ai * bm.w;
      }
    }
    __syncthreads();
  }
  float b0 = bias[tc * 4 + 0], bb1 = bias[tc * 4 + 1];
  float b2v = bias[tc * 4 + 2], b3 = bias[tc * 4 + 3];
#pragma unroll
  for (int i = 0; i < 2; ++i) {
    int gr = r0 + tr * 2 + i;
    if (gr >= M) continue;
    size_t pb = (size_t)gr * 128 + tc * 8;  // feature pairs f=4tc..4tc+3
    *reinterpret_cast<float4*>(&P1[pb]) =
        make_float4(a1r[i][0], a1i[i][0], a1r[i][1], a1i[i][1]);
    *reinterpret_cast<float4*>(&P1[pb + 4]) =
        make_float4(a1r[i][2], a1i[i][2], a1r[i][3], a1i[i][3]);
    *reinterpret_cast<float4*>(&P2[pb]) =
        make_float4(a2r[i][0], a2i[i][0], a2r[i][1], a2i[i][1]);
    *reinterpret_cast<float4*>(&P2[pb + 4]) =
        make_float4(a2r[i][2], a2i[i][2], a2r[i][3], a2i[i][3]);
    size_t hb = (size_t)gr * 64 + tc * 4;
    *reinterpret_cast<float4*>(&Hr[hb]) =
        make_float4(amr[i][0] - ami[i][0] + b0, amr[i][1] - ami[i][1] + bb1,
                    amr[i][2] - ami[i][2] + b2v, amr[i][3] - ami[i][3] + b3);
    *reinterpret_cast<float4*>(&Hi[hb]) =
        make_float4(amr[i][0] + ami[i][0] + b0, amr[i][1] + ami[i][1] + bb1,
                    amr[i][2] + ami[i][2] + b2v, amr[i][3] + ami[i][3] + b3);
  }
}

// ---- A1: hr/hi += T1 (reads P1: (g1r,g1i) pairs) ----------------------------
__global__ __launch_bounds__(256) void k_gA1(
    const int* __restrict__ src, const float2* __restrict__ cf,
    const int* __restrict__ rp, const float* __restrict__ P1,
    float* __restrict__ Hr, float* __restrict__ Hi, int N) {
  int d = blockIdx.x * 4 + (threadIdx.x >> 6);
  if (d >= N) return;
  int lane = threadIdx.x & 63;
  int g = lane >> 5, lg = lane & 31;
  float4 acc = {0, 0, 0, 0};  // hr0, hi0, hr1, hi1
  int k1 = rp[d + 1];
#pragma unroll 2
  for (int k = rp[d] + g; k < k1; k += 2) {
    int s = src[k];
    float2 c = cf[k];
    float4 v = ld4(P1 + (size_t)s * 128 + lg * 4);
    acc.x += c.x * v.x - c.y * v.y;
    acc.y += c.y * v.x + c.x * v.y;
    acc.z += c.x * v.z - c.y * v.w;
    acc.w += c.y * v.z + c.x * v.w;
  }
  acc.x += __shfl_xor(acc.x, 32);
  acc.y += __shfl_xor(acc.y, 32);
  acc.z += __shfl_xor(acc.z, 32);
  acc.w += __shfl_xor(acc.w, 32);
  size_t hb = (size_t)d * 64 + lg * 2;
  if (g == 0) {
    float2 h = ld2(&Hr[hb]);
    *reinterpret_cast<float2*>(&Hr[hb]) = make_float2(h.x + acc.x, h.y + acc.z);
  } else {
    float2 h = ld2(&Hi[hb]);
    *reinterpret_cast<float2*>(&Hi[hb]) = make_float2(h.x + acc.y, h.y + acc.w);
  }
}

// ---- A2: U1/U2 = per-stream prop of g2 (reads P2: (g2r,g2i) pairs) ----------
__global__ __launch_bounds__(256) void k_gA2(
    const int* __restrict__ src, const float2* __restrict__ cf,
    const int* __restrict__ rp, const float* __restrict__ P2,
    float* __restrict__ U1, float* __restrict__ U2, int N) {
  int d = blockIdx.x * 4 + (threadIdx.x >> 6);
  if (d >= N) return;
  int lane = threadIdx.x & 63;
  int g = lane >> 5, lg = lane & 31;
  float4 a01 = {0, 0, 0, 0};  // u0_0, u1_0, u0_1, u1_1
  float4 a23 = {0, 0, 0, 0};  // u2_0, u3_0, u2_1, u3_1
  int k1 = rp[d + 1];
#pragma unroll 2
  for (int k = rp[d] + g; k < k1; k += 2) {
    int s = src[k];
    float2 c = cf[k];
    float4 v = ld4(P2 + (size_t)s * 128 + lg * 4);
    a01.x += c.x * v.x; a01.y += c.y * v.y;
    a01.z += c.x * v.z; a01.w += c.y * v.w;
    a23.x += c.y * v.x; a23.y += c.x * v.y;
    a23.z += c.y * v.z; a23.w += c.x * v.w;
  }
  a01.x += __shfl_xor(a01.x, 32); a01.y += __shfl_xor(a01.y, 32);
  a01.z += __shfl_xor(a01.z, 32); a01.w += __shfl_xor(a01.w, 32);
  a23.x += __shfl_xor(a23.x, 32); a23.y += __shfl_xor(a23.y, 32);
  a23.z += __shfl_xor(a23.z, 32); a23.w += __shfl_xor(a23.w, 32);
  size_t ub = (size_t)d * 128 + lg * 4;
  if (g == 0)
    *reinterpret_cast<float4*>(&U1[ub]) = a01;
  else
    *reinterpret_cast<float4*>(&U2[ub]) = a23;
}

// ---- B1: hr += 2(cr*u0 - ci*u1) (reads U1) ----------------------------------
__global__ __launch_bounds__(256) void k_gB1(
    const int* __restrict__ src, const float2* __restrict__ cf,
    const int* __restrict__ rp, const float* __restrict__ U1,
    float* __restrict__ Hr, int N) {
  int d = blockIdx.x * 4 + (threadIdx.x >> 6);
  if (d >= N) return;
  int lane = threadIdx.x & 63;
  int g = lane >> 5, lg = lane & 31;
  float2 acc = {0, 0};
  int k1 = rp[d + 1];
#pragma unroll 2
  for (int k = rp[d] + g; k < k1; k += 2) {
    int s = src[k];
    float2 c = cf[k];
    float4 v = ld4(U1 + (size_t)s * 128 + lg * 4);
    acc.x += c.x * v.x - c.y * v.y;
    acc.y += c.x * v.z - c.y * v.w;
  }
  acc.x += __shfl_xor(acc.x, 32);
  acc.y += __shfl_xor(acc.y, 32);
  if (g == 0) {
    size_t hb = (size_t)d * 64 + lg * 2;
    float2 h = ld2(&Hr[hb]);
    *reinterpret_cast<float2*>(&Hr[hb]) =
        make_float2(h.x + 2.f * acc.x, h.y + 2.f * acc.y);
  }
}

// ---- B2: hi += 2(ci*u2 + cr*u3), complex ReLU (reads U2, final Hr) ----------
__global__ __launch_bounds__(256) void k_gB2(
    const int* __restrict__ src, const float2* __restrict__ cf,
    const int* __restrict__ rp, const float* __restrict__ U2,
    float* __restrict__ Hr, float* __restrict__ Hi, int N) {
  int d = blockIdx.x * 4 + (threadIdx.x >> 6);
  if (d >= N) return;
  int lane = threadIdx.x & 63;
  int g = lane >> 5, lg = lane & 31;
  float2 acc = {0, 0};
  int k1 = rp[d + 1];
#pragma unroll 2
  for (int k = rp[d] + g; k < k1; k += 2) {
    int s = src[k];
    float2 c = cf[k];
    float4 v = ld4(U2 + (size_t)s * 128 + lg * 4);
    acc.x += c.y * v.x + c.x * v.y;
    acc.y += c.y * v.z + c.x * v.w;
  }
  acc.x += __shfl_xor(acc.x, 32);
  acc.y += __shfl_xor(acc.y, 32);
  if (g == 0) {
    size_t hb = (size_t)d * 64 + lg * 2;
    float2 hr = ld2(&Hr[hb]);
    float2 hi = ld2(&Hi[hb]);
    hi.x += 2.f * acc.x;
    hi.y += 2.f * acc.y;
    if (hr.x < 0.f) { hr.x = 0.f; hi.x = 0.f; }
    if (hr.y < 0.f) { hr.y = 0.f; hi.y = 0.f; }
    *reinterpret_cast<float2*>(&Hr[hb]) = hr;
    *reinterpret_cast<float2*>(&Hi[hb]) = hi;
  }
}

// ---- query gather + linear + log_softmax ------------------------------------
__global__ __launch_bounds__(256) void k_query(
    const int* __restrict__ qe, const float* __restrict__ xr,
    const float* __restrict__ xi, const float* __restrict__ Wlin,
    const float* __restrict__ blin, float* __restrict__ out, int Q) {
  int q = blockIdx.x * 4 + (threadIdx.x >> 6);
  if (q >= Q) return;
  int lane = threadIdx.x & 63;
  int q0 = qe[2 * q], q1 = qe[2 * q + 1];
  float x0 = xr[(size_t)q0 * 64 + lane];
  float x1 = xr[(size_t)q1 * 64 + lane];
  float x2 = xi[(size_t)q0 * 64 + lane];
  float x3 = xi[(size_t)q1 * 64 + lane];
  float l0 = x0 * Wlin[lane] + x1 * Wlin[64 + lane] + x2 * Wlin[128 + lane] + x3 * Wlin[192 + lane];
  float l1 = x0 * Wlin[256 + lane] + x1 * Wlin[320 + lane] + x2 * Wlin[384 + lane] + x3 * Wlin[448 + lane];
#pragma unroll
  for (int o = 32; o > 0; o >>= 1) {
    l0 += __shfl_xor(l0, o);
    l1 += __shfl_xor(l1, o);
  }
  if (lane == 0) {
    l0 += blin[0];
    l1 += blin[1];
    float m = fmaxf(l0, l1);
    float lse = m + logf(expf(l0 - m) + expf(l1 - m));
    out[2 * q + 0] = l0 - lse;
    out[2 * q + 1] = l1 - lse;
  }
}

extern "C" void kernel_launch(void* const* d_in, const int* in_sizes, int n_in,
                              void* d_out, int out_size, void* d_ws, size_t ws_size,
                              hipStream_t stream) {
  const float* real = (const float*)d_in[0];
  const float* imag = (const float*)d_in[1];
  const int* ei     = (const int*)d_in[2];
  const int* qe     = (const int*)d_in[3];
  const float* ew   = (const float*)d_in[4];
  const float* W1   = (const float*)d_in[5];
  const float* b1   = (const float*)d_in[6];
  const float* W2   = (const float*)d_in[7];
  const float* b2   = (const float*)d_in[8];
  const float* Wlin = (const float*)d_in[9];
  const float* blin = (const float*)d_in[10];

  const int N = in_sizes[0] / 128;
  const int E = in_sizes[4];
  const int Q = in_sizes[3] / 2;
  const int* u = ei;
  const int* v = ei + E;

  float* ws = (float*)d_ws;
  size_t off = 0;
  auto alloc = [&](size_t n) { float* p = ws + off; off += n; return p; };
  const size_t N64 = (size_t)N * 64;
  const size_t N128 = (size_t)N * 128;

  float2* cf = (float2*)alloc((size_t)2 * E * 2);                 // 8B-aligned
  unsigned long long* dc = (unsigned long long*)alloc((size_t)2 * N);
  int* src  = (int*)alloc((size_t)2 * E);
  float* P1  = alloc(N128);
  float* P2  = alloc(N128);
  float* U1  = alloc(N128);
  float* U2  = alloc(N128);
  float* HAr = alloc(N64);
  float* HAi = alloc(N64);
  float* HBr = alloc(N64);
  float* HBi = alloc(N64);
  int* rp   = (int*)alloc(N + 1);
  int* nxt  = (int*)alloc(N);
  int* bsum = (int*)alloc(64);
  (void)ws_size; (void)n_in; (void)out_size;

  const int eb = (E + 255) / 256;
  const int mb = (N + 31) / 32;
  const int NB = (N + 1023) / 1024;
  const int gb = (N + 3) / 4;

  // --- graph structure + coefficients ---
  hipMemsetAsync(dc, 0, (size_t)N * 8, stream);
  k_deg_count<<<eb, 256, 0, stream>>>(u, v, ew, dc, E);
  k_scan1<<<NB, 256, 0, stream>>>(dc, rp, bsum, N);
  k_scan2<<<1, 64, 0, stream>>>(bsum, NB);
  k_scan3<<<(N + 256) / 256, 256, 0, stream>>>(rp, nxt, bsum, N, 2 * E);
  k_scatter<<<eb, 256, 0, stream>>>(u, v, ew, dc, nxt, src, cf, E);

  // --- layer 1 (K=128) ---
  k_gemmF<128><<<mb, 256, 0, stream>>>(real, imag, W1, b1, P1, P2, HAr, HAi, N);
  k_gA1<<<gb, 256, 0, stream>>>(src, cf, rp, P1, HAr, HAi, N);
  k_gA2<<<gb, 256, 0, stream>>>(src, cf, rp, P2, U1, U2, N);
  k_gB1<<<gb, 256, 0, stream>>>(src, cf, rp, U1, HAr, N);
  k_gB2<<<gb, 256, 0, stream>>>(src, cf, rp, U2, HAr, HAi, N);

  // --- layer 2 (K=64) ---
  k_gemmF<64><<<mb, 256, 0, stream>>>(HAr, HAi, W2, b2, P1, P2, HBr, HBi, N);
  k_gA1<<<gb, 256, 0, stream>>>(src, cf, rp, P1, HBr, HBi, N);
  k_gA2<<<gb, 256, 0, stream>>>(src, cf, rp, P2, U1, U2, N);
  k_gB1<<<gb, 256, 0, stream>>>(src, cf, rp, U1, HBr, N);
  k_gB2<<<gb, 256, 0, stream>>>(src, cf, rp, U2, HBr, HBi, N);

  // --- queries ---
  k_query<<<(Q + 3) / 4, 256, 0, stream>>>(qe, HBr, HBi, Wlin, blin, (float*)d_out, Q);
}

// Round 8
// 737.887 us; speedup vs baseline: 1.2264x; 1.2038x over previous
//
#include <hip/hip_runtime.h>

// ---------------------------------------------------------------------------
// MagNet link prediction forward, f32 (16-bit quant of propagated streams
// fails: complex-ReLU mask flips amplify tiny hr errors — rounds 3/4).
// Gather (CSR) formulation. Round 8: T1/T2 passes TELESCOPED — same per-edge
// coefficient lets prop(g1)+2*prop(u) fuse into prop(g1+2u):
//   P1[n][128]=(g1r|g1i) pairs, P2[n][128]=(g2r|g2i) pairs  (g=x@W1, x@W2)
//   gU:   U1=(u0,u1), U2=(u2,u3): u0=Σcr*g2r u1=Σci*g2i u2=Σci*g2r u3=Σcr*g2i
//   comb: Z1 = P1 + 2*U1 (in U1), Z2 = P1 + 2*U2 (in U2)      [streaming]
//   gC1:  hr += Σ cr*Z1r - ci*Z1i
//   gC2:  hi += Σ ci*Z2r + cr*Z2i, then complex ReLU
// 3 sparse passes/layer (1536B/edge) instead of 4 (2048B/edge).
// GEMM: BM=64, BK=16, A+W in LDS (22.5KB -> 7 blocks/CU; round-7 global-W
// regressed 95->167us: VMEM issue-bound, not W-bandwidth-bound).
// Reverse edges reuse forward coefficients with ni -> -ni.
// ---------------------------------------------------------------------------

__device__ __forceinline__ float4 ld4(const float* __restrict__ p) {
  return *reinterpret_cast<const float4*>(p);
}
__device__ __forceinline__ float2 ld2(const float* __restrict__ p) {
  return *reinterpret_cast<const float2*>(p);
}

// ---- degree+count in one packed 64-bit atomic -------------------------------
__global__ void k_deg_count(const int* __restrict__ u, const int* __restrict__ v,
                            const float* __restrict__ w,
                            unsigned long long* __restrict__ dc, int E) {
  int e = blockIdx.x * 256 + threadIdx.x;
  if (e >= E) return;
  float hw = 0.5f * w[e];
  unsigned fx = __float2uint_rn(hw * 16777216.f);  // 2^24 fixed point
  unsigned long long pk = (1ULL << 32) | (unsigned long long)fx;
  atomicAdd(&dc[u[e]], pk);
  atomicAdd(&dc[v[e]], pk);
}

// ---- exclusive scan of cnt (= dc>>32) -> rp ---------------------------------
__global__ __launch_bounds__(256) void k_scan1(
    const unsigned long long* __restrict__ dc, int* __restrict__ rp,
    int* __restrict__ bsum, int N) {
  __shared__ int sh[256];
  int t = threadIdx.x;
  int base = blockIdx.x * 1024 + t * 4;
  int c0 = (base + 0 < N) ? (int)(dc[base + 0] >> 32) : 0;
  int c1 = (base + 1 < N) ? (int)(dc[base + 1] >> 32) : 0;
  int c2 = (base + 2 < N) ? (int)(dc[base + 2] >> 32) : 0;
  int c3 = (base + 3 < N) ? (int)(dc[base + 3] >> 32) : 0;
  int s = c0 + c1 + c2 + c3;
  sh[t] = s;
  __syncthreads();
  for (int o = 1; o < 256; o <<= 1) {
    int y = (t >= o) ? sh[t - o] : 0;
    __syncthreads();
    if (t >= o) sh[t] += y;
    __syncthreads();
  }
  int excl = sh[t] - s;
  if (base + 0 < N) rp[base + 0] = excl;
  if (base + 1 < N) rp[base + 1] = excl + c0;
  if (base + 2 < N) rp[base + 2] = excl + c0 + c1;
  if (base + 3 < N) rp[base + 3] = excl + c0 + c1 + c2;
  if (t == 255) bsum[blockIdx.x] = sh[255];
}

__global__ void k_scan2(int* __restrict__ bsum, int NB) {
  if (threadIdx.x == 0 && blockIdx.x == 0) {
    int run = 0;
    for (int i = 0; i < NB; ++i) { int x = bsum[i]; bsum[i] = run; run += x; }
  }
}

__global__ void k_scan3(int* __restrict__ rp, int* __restrict__ nxt,
                        const int* __restrict__ bsum, int N, int twoE) {
  int i = blockIdx.x * 256 + threadIdx.x;
  if (i < N) {
    int val = rp[i] + bsum[i >> 10];
    rp[i] = val;
    nxt[i] = val;
  } else if (i == N) {
    rp[N] = twoE;
  }
}

// ---- scatter edge records: src[pos], cf[pos]=(cr,ci) ------------------------
__global__ void k_scatter(const int* __restrict__ u, const int* __restrict__ v,
                          const float* __restrict__ w,
                          const unsigned long long* __restrict__ dc,
                          int* __restrict__ nxt, int* __restrict__ src,
                          float2* __restrict__ cf, int E) {
  int e = blockIdx.x * 256 + threadIdx.x;
  if (e >= E) return;
  int a = u[e], b = v[e];
  float we = w[e];
  float da = (float)(unsigned)dc[a] * (1.f / 16777216.f);
  float db = (float)(unsigned)dc[b] * (1.f / 16777216.f);
  float ia = da > 0.f ? rsqrtf(da) : 0.f;
  float ib = db > 0.f ? rsqrtf(db) : 0.f;
  float norm = ia * (0.5f * we) * ib;
  float th = 1.57079632679489662f * we;  // 2*pi*q*w, q=0.25
  float sn, cs;
  sincosf(th, &sn, &cs);
  float cr = -norm * cs, ci = -norm * sn;
  int p1 = atomicAdd(&nxt[b], 1);  // forward a->b, coeff (cr, ci)
  src[p1] = a;
  cf[p1] = make_float2(cr, ci);
  int p2 = atomicAdd(&nxt[a], 1);  // reverse b->a, coeff (cr, -ci)
  src[p2] = b;
  cf[p2] = make_float2(cr, -ci);
}

// ---- fused 6-stream GEMM: BM=64, BK=16, A+W in LDS (22.5KB) -----------------
template <int K>
__global__ __launch_bounds__(256) void k_gemmF(
    const float* __restrict__ Ar, const float* __restrict__ Ai,
    const float* __restrict__ W,  // [3][K][64]
    const float* __restrict__ bias,
    float* __restrict__ P1, float* __restrict__ P2,
    float* __restrict__ Hr, float* __restrict__ Hi, int M) {
  __shared__ float Asr[64][20];
  __shared__ float Asi[64][20];
  __shared__ float Ws1[16][64];
  __shared__ float Ws2[16][64];
  __shared__ float Wsm[16][64];
  const int t = threadIdx.x;
  const int r0 = blockIdx.x * 64;
  const int tc = t & 15, tr = t >> 4;
  const float* W0 = W;
  const float* W1 = W + (size_t)K * 64;
  const float* W2 = W + (size_t)2 * K * 64;
  float a1r[4][4] = {}, a1i[4][4] = {}, a2r[4][4] = {}, a2i[4][4] = {};
  float amr[4][4] = {}, ami[4][4] = {};
  for (int k0 = 0; k0 < K; k0 += 16) {
    {  // A tile: 64 rows x 16 k, one float4/thread/array
      int row = t >> 2, c4 = t & 3;
      int gr = r0 + row;
      float4 fr = make_float4(0.f, 0.f, 0.f, 0.f), fi = fr;
      if (gr < M) {
        fr = ld4(&Ar[(size_t)gr * K + k0 + c4 * 4]);
        fi = ld4(&Ai[(size_t)gr * K + k0 + c4 * 4]);
      }
      *reinterpret_cast<float4*>(&Asr[row][c4 * 4]) = fr;
      *reinterpret_cast<float4*>(&Asi[row][c4 * 4]) = fi;
    }
    {  // W tiles: 16 rows x 16 f4 each, one f4/thread/matrix
      int row = t >> 4, c4 = t & 15;
      size_t woff = (size_t)(k0 + row) * 64 + c4 * 4;
      float4 w1 = ld4(&W1[woff]);
      float4 w2 = ld4(&W2[woff]);
      float4 w0 = ld4(&W0[woff]);
      *reinterpret_cast<float4*>(&Ws1[row][c4 * 4]) = w1;
      *reinterpret_cast<float4*>(&Ws2[row][c4 * 4]) = w2;
      *reinterpret_cast<float4*>(&Wsm[row][c4 * 4]) =
          make_float4(w0.x - w2.x, w0.y - w2.y, w0.z - w2.z, w0.w - w2.w);
    }
    __syncthreads();
#pragma unroll 4
    for (int k = 0; k < 16; ++k) {
      float4 b1 = *reinterpret_cast<const float4*>(&Ws1[k][tc * 4]);
      float4 b2 = *reinterpret_cast<const float4*>(&Ws2[k][tc * 4]);
      float4 bm = *reinterpret_cast<const float4*>(&Wsm[k][tc * 4]);
#pragma unroll
      for (int i = 0; i < 4; ++i) {
        float ar = Asr[tr * 4 + i][k], ai = Asi[tr * 4 + i][k];
        a1r[i][0] += ar * b1.x; a1r[i][1] += ar * b1.y; a1r[i][2] += ar * b1.z; a1r[i][3] += ar * b1.w;
        a1i[i][0] += ai * b1.x; a1i[i][1] += ai * b1.y; a1i[i][2] += ai * b1.z; a1i[i][3] += ai * b1.w;
        a2r[i][0] += ar * b2.x; a2r[i][1] += ar * b2.y; a2r[i][2] += ar * b2.z; a2r[i][3] += ar * b2.w;
        a2i[i][0] += ai * b2.x; a2i[i][1] += ai * b2.y; a2i[i][2] += ai * b2.z; a2i[i][3] += ai * b2.w;
        amr[i][0] += ar * bm.x; amr[i][1] += ar * bm.y; amr[i][2] += ar * bm.z; amr[i][3] += ar * bm.w;
        ami[i][0] += ai * bm.x; ami[i][1] += ai * bm.y; ami[i][2] += ai * bm.z; ami[i][3] += ai * bm.w;
      }
    }
    __syncthreads();
  }
  float b0 = bias[tc * 4 + 0], bb1 = bias[tc * 4 + 1];
  float b2v = bias[tc * 4 + 2], b3 = bias[tc * 4 + 3];
#pragma unroll
  for (int i = 0; i < 4; ++i) {
    int gr = r0 + tr * 4 + i;
    if (gr >= M) continue;
    size_t pb = (size_t)gr * 128 + tc * 8;  // feature pairs f=4tc..4tc+3
    *reinterpret_cast<float4*>(&P1[pb]) =
        make_float4(a1r[i][0], a1i[i][0], a1r[i][1], a1i[i][1]);
    *reinterpret_cast<float4*>(&P1[pb + 4]) =
        make_float4(a1r[i][2], a1i[i][2], a1r[i][3], a1i[i][3]);
    *reinterpret_cast<float4*>(&P2[pb]) =
        make_float4(a2r[i][0], a2i[i][0], a2r[i][1], a2i[i][1]);
    *reinterpret_cast<float4*>(&P2[pb + 4]) =
        make_float4(a2r[i][2], a2i[i][2], a2r[i][3], a2i[i][3]);
    size_t hb = (size_t)gr * 64 + tc * 4;
    *reinterpret_cast<float4*>(&Hr[hb]) =
        make_float4(amr[i][0] - ami[i][0] + b0, amr[i][1] - ami[i][1] + bb1,
                    amr[i][2] - ami[i][2] + b2v, amr[i][3] - ami[i][3] + b3);
    *reinterpret_cast<float4*>(&Hi[hb]) =
        make_float4(amr[i][0] + ami[i][0] + b0, amr[i][1] + ami[i][1] + bb1,
                    amr[i][2] + ami[i][2] + b2v, amr[i][3] + ami[i][3] + b3);
  }
}

// ---- gU: U1=(u0,u1), U2=(u2,u3) = per-stream prop of g2 (reads P2) ----------
__global__ __launch_bounds__(256) void k_gU(
    const int* __restrict__ src, const float2* __restrict__ cf,
    const int* __restrict__ rp, const float* __restrict__ P2,
    float* __restrict__ U1, float* __restrict__ U2, int N) {
  int d = blockIdx.x * 4 + (threadIdx.x >> 6);
  if (d >= N) return;
  int lane = threadIdx.x & 63;
  int g = lane >> 5, lg = lane & 31;
  float4 a01 = {0, 0, 0, 0};  // u0_0, u1_0, u0_1, u1_1
  float4 a23 = {0, 0, 0, 0};  // u2_0, u3_0, u2_1, u3_1
  int k1 = rp[d + 1];
#pragma unroll 2
  for (int k = rp[d] + g; k < k1; k += 2) {
    int s = src[k];
    float2 c = cf[k];
    float4 v = ld4(P2 + (size_t)s * 128 + lg * 4);
    a01.x += c.x * v.x; a01.y += c.y * v.y;
    a01.z += c.x * v.z; a01.w += c.y * v.w;
    a23.x += c.y * v.x; a23.y += c.x * v.y;
    a23.z += c.y * v.z; a23.w += c.x * v.w;
  }
  a01.x += __shfl_xor(a01.x, 32); a01.y += __shfl_xor(a01.y, 32);
  a01.z += __shfl_xor(a01.z, 32); a01.w += __shfl_xor(a01.w, 32);
  a23.x += __shfl_xor(a23.x, 32); a23.y += __shfl_xor(a23.y, 32);
  a23.z += __shfl_xor(a23.z, 32); a23.w += __shfl_xor(a23.w, 32);
  size_t ub = (size_t)d * 128 + lg * 4;
  if (g == 0)
    *reinterpret_cast<float4*>(&U1[ub]) = a01;
  else
    *reinterpret_cast<float4*>(&U2[ub]) = a23;
}

// ---- comb: Z1 = P1 + 2*U1 (into U1), Z2 = P1 + 2*U2 (into U2) ---------------
__global__ void k_comb(const float* __restrict__ P1, float* __restrict__ U1,
                       float* __restrict__ U2, int n4) {
  int i = blockIdx.x * 256 + threadIdx.x;
  if (i >= n4) return;
  float4 p = ld4(P1 + (size_t)i * 4);
  float4 a = ld4(U1 + (size_t)i * 4);
  float4 b = ld4(U2 + (size_t)i * 4);
  *reinterpret_cast<float4*>(&U1[(size_t)i * 4]) =
      make_float4(p.x + 2.f * a.x, p.y + 2.f * a.y, p.z + 2.f * a.z, p.w + 2.f * a.w);
  *reinterpret_cast<float4*>(&U2[(size_t)i * 4]) =
      make_float4(p.x + 2.f * b.x, p.y + 2.f * b.y, p.z + 2.f * b.z, p.w + 2.f * b.w);
}

// ---- gC1: hr += sum cr*Z1r - ci*Z1i (reads Z1) ------------------------------
__global__ __launch_bounds__(256) void k_gC1(
    const int* __restrict__ src, const float2* __restrict__ cf,
    const int* __restrict__ rp, const float* __restrict__ Z1,
    float* __restrict__ Hr, int N) {
  int d = blockIdx.x * 4 + (threadIdx.x >> 6);
  if (d >= N) return;
  int lane = threadIdx.x & 63;
  int g = lane >> 5, lg = lane & 31;
  float2 acc = {0, 0};
  int k1 = rp[d + 1];
#pragma unroll 2
  for (int k = rp[d] + g; k < k1; k += 2) {
    int s = src[k];
    float2 c = cf[k];
    float4 v = ld4(Z1 + (size_t)s * 128 + lg * 4);
    acc.x += c.x * v.x - c.y * v.y;
    acc.y += c.x * v.z - c.y * v.w;
  }
  acc.x += __shfl_xor(acc.x, 32);
  acc.y += __shfl_xor(acc.y, 32);
  if (g == 0) {
    size_t hb = (size_t)d * 64 + lg * 2;
    float2 h = ld2(&Hr[hb]);
    *reinterpret_cast<float2*>(&Hr[hb]) = make_float2(h.x + acc.x, h.y + acc.y);
  }
}

// ---- gC2: hi += sum ci*Z2r + cr*Z2i, complex ReLU (reads Z2, final Hr) ------
__global__ __launch_bounds__(256) void k_gC2(
    const int* __restrict__ src, const float2* __restrict__ cf,
    const int* __restrict__ rp, const float* __restrict__ Z2,
    float* __restrict__ Hr, float* __restrict__ Hi, int N) {
  int d = blockIdx.x * 4 + (threadIdx.x >> 6);
  if (d >= N) return;
  int lane = threadIdx.x & 63;
  int g = lane >> 5, lg = lane & 31;
  float2 acc = {0, 0};
  int k1 = rp[d + 1];
#pragma unroll 2
  for (int k = rp[d] + g; k < k1; k += 2) {
    int s = src[k];
    float2 c = cf[k];
    float4 v = ld4(Z2 + (size_t)s * 128 + lg * 4);
    acc.x += c.y * v.x + c.x * v.y;
    acc.y += c.y * v.z + c.x * v.w;
  }
  acc.x += __shfl_xor(acc.x, 32);
  acc.y += __shfl_xor(acc.y, 32);
  if (g == 0) {
    size_t hb = (size_t)d * 64 + lg * 2;
    float2 hr = ld2(&Hr[hb]);
    float2 hi = ld2(&Hi[hb]);
    hi.x += acc.x;
    hi.y += acc.y;
    if (hr.x < 0.f) { hr.x = 0.f; hi.x = 0.f; }
    if (hr.y < 0.f) { hr.y = 0.f; hi.y = 0.f; }
    *reinterpret_cast<float2*>(&Hr[hb]) = hr;
    *reinterpret_cast<float2*>(&Hi[hb]) = hi;
  }
}

// ---- query gather + linear + log_softmax ------------------------------------
__global__ __launch_bounds__(256) void k_query(
    const int* __restrict__ qe, const float* __restrict__ xr,
    const float* __restrict__ xi, const float* __restrict__ Wlin,
    const float* __restrict__ blin, float* __restrict__ out, int Q) {
  int q = blockIdx.x * 4 + (threadIdx.x >> 6);
  if (q >= Q) return;
  int lane = threadIdx.x & 63;
  int q0 = qe[2 * q], q1 = qe[2 * q + 1];
  float x0 = xr[(size_t)q0 * 64 + lane];
  float x1 = xr[(size_t)q1 * 64 + lane];
  float x2 = xi[(size_t)q0 * 64 + lane];
  float x3 = xi[(size_t)q1 * 64 + lane];
  float l0 = x0 * Wlin[lane] + x1 * Wlin[64 + lane] + x2 * Wlin[128 + lane] + x3 * Wlin[192 + lane];
  float l1 = x0 * Wlin[256 + lane] + x1 * Wlin[320 + lane] + x2 * Wlin[384 + lane] + x3 * Wlin[448 + lane];
#pragma unroll
  for (int o = 32; o > 0; o >>= 1) {
    l0 += __shfl_xor(l0, o);
    l1 += __shfl_xor(l1, o);
  }
  if (lane == 0) {
    l0 += blin[0];
    l1 += blin[1];
    float m = fmaxf(l0, l1);
    float lse = m + logf(expf(l0 - m) + expf(l1 - m));
    out[2 * q + 0] = l0 - lse;
    out[2 * q + 1] = l1 - lse;
  }
}

extern "C" void kernel_launch(void* const* d_in, const int* in_sizes, int n_in,
                              void* d_out, int out_size, void* d_ws, size_t ws_size,
                              hipStream_t stream) {
  const float* real = (const float*)d_in[0];
  const float* imag = (const float*)d_in[1];
  const int* ei     = (const int*)d_in[2];
  const int* qe     = (const int*)d_in[3];
  const float* ew   = (const float*)d_in[4];
  const float* W1   = (const float*)d_in[5];
  const float* b1   = (const float*)d_in[6];
  const float* W2   = (const float*)d_in[7];
  const float* b2   = (const float*)d_in[8];
  const float* Wlin = (const float*)d_in[9];
  const float* blin = (const float*)d_in[10];

  const int N = in_sizes[0] / 128;
  const int E = in_sizes[4];
  const int Q = in_sizes[3] / 2;
  const int* u = ei;
  const int* v = ei + E;

  float* ws = (float*)d_ws;
  size_t off = 0;
  auto alloc = [&](size_t n) { float* p = ws + off; off += n; return p; };
  const size_t N64 = (size_t)N * 64;
  const size_t N128 = (size_t)N * 128;

  float2* cf = (float2*)alloc((size_t)2 * E * 2);                 // 8B-aligned
  unsigned long long* dc = (unsigned long long*)alloc((size_t)2 * N);
  int* src  = (int*)alloc((size_t)2 * E);
  float* P1  = alloc(N128);
  float* P2  = alloc(N128);
  float* U1  = alloc(N128);   // becomes Z1 after k_comb
  float* U2  = alloc(N128);   // becomes Z2 after k_comb
  float* HAr = alloc(N64);
  float* HAi = alloc(N64);
  float* HBr = alloc(N64);
  float* HBi = alloc(N64);
  int* rp   = (int*)alloc(N + 1);
  int* nxt  = (int*)alloc(N);
  int* bsum = (int*)alloc(64);
  (void)ws_size; (void)n_in; (void)out_size;

  const int eb = (E + 255) / 256;
  const int mb = (N + 63) / 64;
  const int NB = (N + 1023) / 1024;
  const int gb = (N + 3) / 4;
  const int n4 = (int)(N128 / 4);
  const int cb = (n4 + 255) / 256;

  // --- graph structure + coefficients ---
  hipMemsetAsync(dc, 0, (size_t)N * 8, stream);
  k_deg_count<<<eb, 256, 0, stream>>>(u, v, ew, dc, E);
  k_scan1<<<NB, 256, 0, stream>>>(dc, rp, bsum, N);
  k_scan2<<<1, 64, 0, stream>>>(bsum, NB);
  k_scan3<<<(N + 256) / 256, 256, 0, stream>>>(rp, nxt, bsum, N, 2 * E);
  k_scatter<<<eb, 256, 0, stream>>>(u, v, ew, dc, nxt, src, cf, E);

  // --- layer 1 (K=128) ---
  k_gemmF<128><<<mb, 256, 0, stream>>>(real, imag, W1, b1, P1, P2, HAr, HAi, N);
  k_gU<<<gb, 256, 0, stream>>>(src, cf, rp, P2, U1, U2, N);
  k_comb<<<cb, 256, 0, stream>>>(P1, U1, U2, n4);
  k_gC1<<<gb, 256, 0, stream>>>(src, cf, rp, U1, HAr, N);
  k_gC2<<<gb, 256, 0, stream>>>(src, cf, rp, U2, HAr, HAi, N);

  // --- layer 2 (K=64) ---
  k_gemmF<64><<<mb, 256, 0, stream>>>(HAr, HAi, W2, b2, P1, P2, HBr, HBi, N);
  k_gU<<<gb, 256, 0, stream>>>(src, cf, rp, P2, U1, U2, N);
  k_comb<<<cb, 256, 0, stream>>>(P1, U1, U2, n4);
  k_gC1<<<gb, 256, 0, stream>>>(src, cf, rp, U1, HBr, N);
  k_gC2<<<gb, 256, 0, stream>>>(src, cf, rp, U2, HBr, HBi, N);

  // --- queries ---
  k_query<<<(Q + 3) / 4, 256, 0, stream>>>(qe, HBr, HBi, Wlin, blin, (float*)d_out, Q);
}

// Round 9
// 685.710 us; speedup vs baseline: 1.3197x; 1.0761x over previous
//
#include <hip/hip_runtime.h>

// ---------------------------------------------------------------------------
// MagNet link prediction forward, f32 (16-bit quant of propagated streams
// fails: complex-ReLU mask flips amplify tiny hr errors — rounds 3/4).
// Gather (CSR) formulation, telescoped Chebyshev passes (round 8):
//   out = x@(W0-W2) + b + prop(g1 + 2*prop(g2)),  g1=x@W1, g2=x@W2
// Round 9:
//   gU:  u-streams of prop(g2) + FUSED comb epilogue -> Z[n][256] =
//        [ (g1r+2u0, g1i+2u1) pairs | (g1r+2u2, g1i+2u3) pairs ]
//   gC:  single pass reads 1KB Z row/edge: hr += cr*z1r - ci*z1i,
//        hi += ci*z2r + cr*z2i, then complex ReLU inline.
//   GEMM: BM=32 (grid 1563 — round-8's BM=64 grid of 782 = 3 blocks/CU was
//   the occupancy cap), BK=32, A+W in LDS with round-6's conflict-free pads.
// Reverse edges reuse forward coefficients with ni -> -ni.
// ---------------------------------------------------------------------------

__device__ __forceinline__ float4 ld4(const float* __restrict__ p) {
  return *reinterpret_cast<const float4*>(p);
}
__device__ __forceinline__ float2 ld2(const float* __restrict__ p) {
  return *reinterpret_cast<const float2*>(p);
}

// ---- degree+count in one packed 64-bit atomic -------------------------------
__global__ void k_deg_count(const int* __restrict__ u, const int* __restrict__ v,
                            const float* __restrict__ w,
                            unsigned long long* __restrict__ dc, int E) {
  int e = blockIdx.x * 256 + threadIdx.x;
  if (e >= E) return;
  float hw = 0.5f * w[e];
  unsigned fx = __float2uint_rn(hw * 16777216.f);  // 2^24 fixed point
  unsigned long long pk = (1ULL << 32) | (unsigned long long)fx;
  atomicAdd(&dc[u[e]], pk);
  atomicAdd(&dc[v[e]], pk);
}

// ---- exclusive scan of cnt (= dc>>32) -> rp ---------------------------------
__global__ __launch_bounds__(256) void k_scan1(
    const unsigned long long* __restrict__ dc, int* __restrict__ rp,
    int* __restrict__ bsum, int N) {
  __shared__ int sh[256];
  int t = threadIdx.x;
  int base = blockIdx.x * 1024 + t * 4;
  int c0 = (base + 0 < N) ? (int)(dc[base + 0] >> 32) : 0;
  int c1 = (base + 1 < N) ? (int)(dc[base + 1] >> 32) : 0;
  int c2 = (base + 2 < N) ? (int)(dc[base + 2] >> 32) : 0;
  int c3 = (base + 3 < N) ? (int)(dc[base + 3] >> 32) : 0;
  int s = c0 + c1 + c2 + c3;
  sh[t] = s;
  __syncthreads();
  for (int o = 1; o < 256; o <<= 1) {
    int y = (t >= o) ? sh[t - o] : 0;
    __syncthreads();
    if (t >= o) sh[t] += y;
    __syncthreads();
  }
  int excl = sh[t] - s;
  if (base + 0 < N) rp[base + 0] = excl;
  if (base + 1 < N) rp[base + 1] = excl + c0;
  if (base + 2 < N) rp[base + 2] = excl + c0 + c1;
  if (base + 3 < N) rp[base + 3] = excl + c0 + c1 + c2;
  if (t == 255) bsum[blockIdx.x] = sh[255];
}

__global__ void k_scan2(int* __restrict__ bsum, int NB) {
  if (threadIdx.x == 0 && blockIdx.x == 0) {
    int run = 0;
    for (int i = 0; i < NB; ++i) { int x = bsum[i]; bsum[i] = run; run += x; }
  }
}

__global__ void k_scan3(int* __restrict__ rp, int* __restrict__ nxt,
                        const int* __restrict__ bsum, int N, int twoE) {
  int i = blockIdx.x * 256 + threadIdx.x;
  if (i < N) {
    int val = rp[i] + bsum[i >> 10];
    rp[i] = val;
    nxt[i] = val;
  } else if (i == N) {
    rp[N] = twoE;
  }
}

// ---- scatter edge records: src[pos], cf[pos]=(cr,ci) ------------------------
__global__ void k_scatter(const int* __restrict__ u, const int* __restrict__ v,
                          const float* __restrict__ w,
                          const unsigned long long* __restrict__ dc,
                          int* __restrict__ nxt, int* __restrict__ src,
                          float2* __restrict__ cf, int E) {
  int e = blockIdx.x * 256 + threadIdx.x;
  if (e >= E) return;
  int a = u[e], b = v[e];
  float we = w[e];
  float da = (float)(unsigned)dc[a] * (1.f / 16777216.f);
  float db = (float)(unsigned)dc[b] * (1.f / 16777216.f);
  float ia = da > 0.f ? rsqrtf(da) : 0.f;
  float ib = db > 0.f ? rsqrtf(db) : 0.f;
  float norm = ia * (0.5f * we) * ib;
  float th = 1.57079632679489662f * we;  // 2*pi*q*w, q=0.25
  float sn, cs;
  sincosf(th, &sn, &cs);
  float cr = -norm * cs, ci = -norm * sn;
  int p1 = atomicAdd(&nxt[b], 1);  // forward a->b, coeff (cr, ci)
  src[p1] = a;
  cf[p1] = make_float2(cr, ci);
  int p2 = atomicAdd(&nxt[a], 1);  // reverse b->a, coeff (cr, -ci)
  src[p2] = b;
  cf[p2] = make_float2(cr, -ci);
}

// ---- fused 6-stream GEMM: BM=32, BK=32, A+W in LDS (33.8KB, grid 2x) --------
template <int K>
__global__ __launch_bounds__(256) void k_gemmF(
    const float* __restrict__ Ar, const float* __restrict__ Ai,
    const float* __restrict__ W,  // [3][K][64]
    const float* __restrict__ bias,
    float* __restrict__ P1, float* __restrict__ P2,
    float* __restrict__ Hr, float* __restrict__ Hi, int M) {
  __shared__ float Asr[32][36];
  __shared__ float Asi[32][36];
  __shared__ float Ws1[32][64];
  __shared__ float Ws2[32][64];
  __shared__ float Wsm[32][64];
  const int t = threadIdx.x;
  const int r0 = blockIdx.x * 32;
  const int tc = t & 15, tr = t >> 4;
  const float* W0 = W;
  const float* W1 = W + (size_t)K * 64;
  const float* W2 = W + (size_t)2 * K * 64;
  float a1r[2][4] = {}, a1i[2][4] = {}, a2r[2][4] = {}, a2i[2][4] = {};
  float amr[2][4] = {}, ami[2][4] = {};
  for (int k0 = 0; k0 < K; k0 += 32) {
    {  // A tile: 32 rows x 8 float4, one per thread per array
      int row = t >> 3, c4 = t & 7;
      int gr = r0 + row;
      float4 fr = make_float4(0.f, 0.f, 0.f, 0.f), fi = fr;
      if (gr < M) {
        fr = ld4(&Ar[(size_t)gr * K + k0 + c4 * 4]);
        fi = ld4(&Ai[(size_t)gr * K + k0 + c4 * 4]);
      }
      *reinterpret_cast<float4*>(&Asr[row][c4 * 4]) = fr;
      *reinterpret_cast<float4*>(&Asi[row][c4 * 4]) = fi;
    }
    for (int li = t; li < 512; li += 256) {  // W tiles: 32 rows x 16 f4 each
      int row = li >> 4, c4 = li & 15;
      size_t woff = (size_t)(k0 + row) * 64 + c4 * 4;
      float4 w1 = ld4(&W1[woff]);
      float4 w2 = ld4(&W2[woff]);
      float4 w0 = ld4(&W0[woff]);
      *reinterpret_cast<float4*>(&Ws1[row][c4 * 4]) = w1;
      *reinterpret_cast<float4*>(&Ws2[row][c4 * 4]) = w2;
      *reinterpret_cast<float4*>(&Wsm[row][c4 * 4]) =
          make_float4(w0.x - w2.x, w0.y - w2.y, w0.z - w2.z, w0.w - w2.w);
    }
    __syncthreads();
#pragma unroll 4
    for (int k = 0; k < 32; ++k) {
      float4 b1 = *reinterpret_cast<const float4*>(&Ws1[k][tc * 4]);
      float4 b2 = *reinterpret_cast<const float4*>(&Ws2[k][tc * 4]);
      float4 bm = *reinterpret_cast<const float4*>(&Wsm[k][tc * 4]);
#pragma unroll
      for (int i = 0; i < 2; ++i) {
        float ar = Asr[tr * 2 + i][k], ai = Asi[tr * 2 + i][k];
        a1r[i][0] += ar * b1.x; a1r[i][1] += ar * b1.y; a1r[i][2] += ar * b1.z; a1r[i][3] += ar * b1.w;
        a1i[i][0] += ai * b1.x; a1i[i][1] += ai * b1.y; a1i[i][2] += ai * b1.z; a1i[i][3] += ai * b1.w;
        a2r[i][0] += ar * b2.x; a2r[i][1] += ar * b2.y; a2r[i][2] += ar * b2.z; a2r[i][3] += ar * b2.w;
        a2i[i][0] += ai * b2.x; a2i[i][1] += ai * b2.y; a2i[i][2] += ai * b2.z; a2i[i][3] += ai * b2.w;
        amr[i][0] += ar * bm.x; amr[i][1] += ar * bm.y; amr[i][2] += ar * bm.z; amr[i][3] += ar * bm.w;
        ami[i][0] += ai * bm.x; ami[i][1] += ai * bm.y; ami[i][2] += ai * bm.z; ami[i][3] += ai * bm.w;
      }
    }
    __syncthreads();
  }
  float b0 = bias[tc * 4 + 0], bb1 = bias[tc * 4 + 1];
  float b2v = bias[tc * 4 + 2], b3 = bias[tc * 4 + 3];
#pragma unroll
  for (int i = 0; i < 2; ++i) {
    int gr = r0 + tr * 2 + i;
    if (gr >= M) continue;
    size_t pb = (size_t)gr * 128 + tc * 8;  // feature pairs f=4tc..4tc+3
    *reinterpret_cast<float4*>(&P1[pb]) =
        make_float4(a1r[i][0], a1i[i][0], a1r[i][1], a1i[i][1]);
    *reinterpret_cast<float4*>(&P1[pb + 4]) =
        make_float4(a1r[i][2], a1i[i][2], a1r[i][3], a1i[i][3]);
    *reinterpret_cast<float4*>(&P2[pb]) =
        make_float4(a2r[i][0], a2i[i][0], a2r[i][1], a2i[i][1]);
    *reinterpret_cast<float4*>(&P2[pb + 4]) =
        make_float4(a2r[i][2], a2i[i][2], a2r[i][3], a2i[i][3]);
    size_t hb = (size_t)gr * 64 + tc * 4;
    *reinterpret_cast<float4*>(&Hr[hb]) =
        make_float4(amr[i][0] - ami[i][0] + b0, amr[i][1] - ami[i][1] + bb1,
                    amr[i][2] - ami[i][2] + b2v, amr[i][3] - ami[i][3] + b3);
    *reinterpret_cast<float4*>(&Hi[hb]) =
        make_float4(amr[i][0] + ami[i][0] + b0, amr[i][1] + ami[i][1] + bb1,
                    amr[i][2] + ami[i][2] + b2v, amr[i][3] + ami[i][3] + b3);
  }
}

// ---- gU: u-streams of prop(g2) + fused comb: Z = [P1+2*(u0,u1) | P1+2*(u2,u3)]
__global__ __launch_bounds__(256) void k_gU(
    const int* __restrict__ src, const float2* __restrict__ cf,
    const int* __restrict__ rp, const float* __restrict__ P2,
    const float* __restrict__ P1, float* __restrict__ Z, int N) {
  int d = blockIdx.x * 4 + (threadIdx.x >> 6);
  if (d >= N) return;
  int lane = threadIdx.x & 63;
  int g = lane >> 5, lg = lane & 31;
  float4 a01 = {0, 0, 0, 0};  // u0_f0, u1_f0, u0_f1, u1_f1
  float4 a23 = {0, 0, 0, 0};  // u2_f0, u3_f0, u2_f1, u3_f1
  int k1 = rp[d + 1];
#pragma unroll 2
  for (int k = rp[d] + g; k < k1; k += 2) {
    int s = src[k];
    float2 c = cf[k];
    float4 v = ld4(P2 + (size_t)s * 128 + lg * 4);
    a01.x += c.x * v.x; a01.y += c.y * v.y;
    a01.z += c.x * v.z; a01.w += c.y * v.w;
    a23.x += c.y * v.x; a23.y += c.x * v.y;
    a23.z += c.y * v.z; a23.w += c.x * v.w;
  }
  a01.x += __shfl_xor(a01.x, 32); a01.y += __shfl_xor(a01.y, 32);
  a01.z += __shfl_xor(a01.z, 32); a01.w += __shfl_xor(a01.w, 32);
  a23.x += __shfl_xor(a23.x, 32); a23.y += __shfl_xor(a23.y, 32);
  a23.z += __shfl_xor(a23.z, 32); a23.w += __shfl_xor(a23.w, 32);
  float4 p = ld4(P1 + (size_t)d * 128 + lg * 4);
  size_t zb = (size_t)d * 256 + lg * 4;
  if (g == 0)
    *reinterpret_cast<float4*>(&Z[zb]) =
        make_float4(p.x + 2.f * a01.x, p.y + 2.f * a01.y,
                    p.z + 2.f * a01.z, p.w + 2.f * a01.w);
  else
    *reinterpret_cast<float4*>(&Z[zb + 128]) =
        make_float4(p.x + 2.f * a23.x, p.y + 2.f * a23.y,
                    p.z + 2.f * a23.z, p.w + 2.f * a23.w);
}

// ---- gC: hr += cr*z1r - ci*z1i; hi += ci*z2r + cr*z2i; complex ReLU ---------
__global__ __launch_bounds__(256) void k_gC(
    const int* __restrict__ src, const float2* __restrict__ cf,
    const int* __restrict__ rp, const float* __restrict__ Z,
    float* __restrict__ Hr, float* __restrict__ Hi, int N) {
  int d = blockIdx.x * 4 + (threadIdx.x >> 6);
  if (d >= N) return;
  int lane = threadIdx.x & 63;
  int g = lane >> 5, lg = lane & 31;
  float2 ahr = {0, 0}, ahi = {0, 0};
  int k1 = rp[d + 1];
#pragma unroll 2
  for (int k = rp[d] + g; k < k1; k += 2) {
    int s = src[k];
    float2 c = cf[k];
    const float* row = Z + (size_t)s * 256 + lg * 4;
    float4 z1 = ld4(row);
    float4 z2 = ld4(row + 128);
    ahr.x += c.x * z1.x - c.y * z1.y;
    ahr.y += c.x * z1.z - c.y * z1.w;
    ahi.x += c.y * z2.x + c.x * z2.y;
    ahi.y += c.y * z2.z + c.x * z2.w;
  }
  ahr.x += __shfl_xor(ahr.x, 32);
  ahr.y += __shfl_xor(ahr.y, 32);
  ahi.x += __shfl_xor(ahi.x, 32);
  ahi.y += __shfl_xor(ahi.y, 32);
  if (g == 0) {
    size_t hb = (size_t)d * 64 + lg * 2;
    float2 hr = ld2(&Hr[hb]);
    float2 hi = ld2(&Hi[hb]);
    hr.x += ahr.x; hr.y += ahr.y;
    hi.x += ahi.x; hi.y += ahi.y;
    if (hr.x < 0.f) { hr.x = 0.f; hi.x = 0.f; }
    if (hr.y < 0.f) { hr.y = 0.f; hi.y = 0.f; }
    *reinterpret_cast<float2*>(&Hr[hb]) = hr;
    *reinterpret_cast<float2*>(&Hi[hb]) = hi;
  }
}

// ---- query gather + linear + log_softmax ------------------------------------
__global__ __launch_bounds__(256) void k_query(
    const int* __restrict__ qe, const float* __restrict__ xr,
    const float* __restrict__ xi, const float* __restrict__ Wlin,
    const float* __restrict__ blin, float* __restrict__ out, int Q) {
  int q = blockIdx.x * 4 + (threadIdx.x >> 6);
  if (q >= Q) return;
  int lane = threadIdx.x & 63;
  int q0 = qe[2 * q], q1 = qe[2 * q + 1];
  float x0 = xr[(size_t)q0 * 64 + lane];
  float x1 = xr[(size_t)q1 * 64 + lane];
  float x2 = xi[(size_t)q0 * 64 + lane];
  float x3 = xi[(size_t)q1 * 64 + lane];
  float l0 = x0 * Wlin[lane] + x1 * Wlin[64 + lane] + x2 * Wlin[128 + lane] + x3 * Wlin[192 + lane];
  float l1 = x0 * Wlin[256 + lane] + x1 * Wlin[320 + lane] + x2 * Wlin[384 + lane] + x3 * Wlin[448 + lane];
#pragma unroll
  for (int o = 32; o > 0; o >>= 1) {
    l0 += __shfl_xor(l0, o);
    l1 += __shfl_xor(l1, o);
  }
  if (lane == 0) {
    l0 += blin[0];
    l1 += blin[1];
    float m = fmaxf(l0, l1);
    float lse = m + logf(expf(l0 - m) + expf(l1 - m));
    out[2 * q + 0] = l0 - lse;
    out[2 * q + 1] = l1 - lse;
  }
}

extern "C" void kernel_launch(void* const* d_in, const int* in_sizes, int n_in,
                              void* d_out, int out_size, void* d_ws, size_t ws_size,
                              hipStream_t stream) {
  const float* real = (const float*)d_in[0];
  const float* imag = (const float*)d_in[1];
  const int* ei     = (const int*)d_in[2];
  const int* qe     = (const int*)d_in[3];
  const float* ew   = (const float*)d_in[4];
  const float* W1   = (const float*)d_in[5];
  const float* b1   = (const float*)d_in[6];
  const float* W2   = (const float*)d_in[7];
  const float* b2   = (const float*)d_in[8];
  const float* Wlin = (const float*)d_in[9];
  const float* blin = (const float*)d_in[10];

  const int N = in_sizes[0] / 128;
  const int E = in_sizes[4];
  const int Q = in_sizes[3] / 2;
  const int* u = ei;
  const int* v = ei + E;

  float* ws = (float*)d_ws;
  size_t off = 0;
  auto alloc = [&](size_t n) { float* p = ws + off; off += n; return p; };
  const size_t N64 = (size_t)N * 64;
  const size_t N128 = (size_t)N * 128;
  const size_t N256 = (size_t)N * 256;

  float2* cf = (float2*)alloc((size_t)2 * E * 2);                 // 8B-aligned
  unsigned long long* dc = (unsigned long long*)alloc((size_t)2 * N);
  int* src  = (int*)alloc((size_t)2 * E);
  float* P1  = alloc(N128);
  float* P2  = alloc(N128);
  float* Z   = alloc(N256);
  float* HAr = alloc(N64);
  float* HAi = alloc(N64);
  float* HBr = alloc(N64);
  float* HBi = alloc(N64);
  int* rp   = (int*)alloc(N + 1);
  int* nxt  = (int*)alloc(N);
  int* bsum = (int*)alloc(64);
  (void)ws_size; (void)n_in; (void)out_size;

  const int eb = (E + 255) / 256;
  const int mb = (N + 31) / 32;
  const int NB = (N + 1023) / 1024;
  const int gb = (N + 3) / 4;

  // --- graph structure + coefficients ---
  hipMemsetAsync(dc, 0, (size_t)N * 8, stream);
  k_deg_count<<<eb, 256, 0, stream>>>(u, v, ew, dc, E);
  k_scan1<<<NB, 256, 0, stream>>>(dc, rp, bsum, N);
  k_scan2<<<1, 64, 0, stream>>>(bsum, NB);
  k_scan3<<<(N + 256) / 256, 256, 0, stream>>>(rp, nxt, bsum, N, 2 * E);
  k_scatter<<<eb, 256, 0, stream>>>(u, v, ew, dc, nxt, src, cf, E);

  // --- layer 1 (K=128) ---
  k_gemmF<128><<<mb, 256, 0, stream>>>(real, imag, W1, b1, P1, P2, HAr, HAi, N);
  k_gU<<<gb, 256, 0, stream>>>(src, cf, rp, P2, P1, Z, N);
  k_gC<<<gb, 256, 0, stream>>>(src, cf, rp, Z, HAr, HAi, N);

  // --- layer 2 (K=64) ---
  k_gemmF<64><<<mb, 256, 0, stream>>>(HAr, HAi, W2, b2, P1, P2, HBr, HBi, N);
  k_gU<<<gb, 256, 0, stream>>>(src, cf, rp, P2, P1, Z, N);
  k_gC<<<gb, 256, 0, stream>>>(src, cf, rp, Z, HBr, HBi, N);

  // --- queries ---
  k_query<<<(Q + 3) / 4, 256, 0, stream>>>(qe, HBr, HBi, Wlin, blin, (float*)d_out, Q);
}